// Round 1
// baseline (898.132 us; speedup 1.0000x reference)
//
#include <hip/hip_runtime.h>
#include <hip/hip_bf16.h>

#define N_NODES 131072
#define N_PER   1024
#define NGRAPH  128
#define N_EDGES 2097152
#define KSP     30
#define HID     128
#define IN_CH   14
#define OUT_DIM 4

// ---------------- CSR build ----------------
__global__ __launch_bounds__(256) void k_count_deg(const int* __restrict__ dst, int* __restrict__ deg){
  int e = blockIdx.x*256 + threadIdx.x;
  if (e < N_EDGES) atomicAdd(&deg[dst[e]], 1);
}

__global__ __launch_bounds__(256) void k_scan1(const int* __restrict__ deg, int* __restrict__ row_ptr,
                                               float* __restrict__ deg_inv, int* __restrict__ bsum){
  __shared__ int sh[256];
  int t = threadIdx.x;
  int e = blockIdx.x*256 + t;
  int d = deg[e];
  sh[t] = d; __syncthreads();
  for (int ofs=1; ofs<256; ofs<<=1){
    int v = sh[t];
    int add = (t>=ofs) ? sh[t-ofs] : 0;
    __syncthreads();
    sh[t] = v + add;
    __syncthreads();
  }
  row_ptr[e] = sh[t] - d;                       // block-local exclusive
  deg_inv[e] = d > 0 ? 1.0f/(float)d : 0.0f;
  if (t==255) bsum[blockIdx.x] = sh[255];
}

__global__ __launch_bounds__(512) void k_scan2(int* __restrict__ bsum, int* __restrict__ row_ptr){
  __shared__ int sh[512];
  int t = threadIdx.x;
  int v0 = bsum[t];
  sh[t] = v0; __syncthreads();
  for (int ofs=1; ofs<512; ofs<<=1){
    int v = sh[t];
    int add = (t>=ofs) ? sh[t-ofs] : 0;
    __syncthreads();
    sh[t] = v + add;
    __syncthreads();
  }
  bsum[t] = sh[t] - v0;                         // exclusive block offsets
  if (t==511) row_ptr[N_NODES] = sh[511];       // total edge count
}

__global__ __launch_bounds__(256) void k_scan3(int* __restrict__ row_ptr, const int* __restrict__ bsum){
  int e = blockIdx.x*256 + threadIdx.x;
  row_ptr[e] += bsum[blockIdx.x];
}

__global__ __launch_bounds__(256) void k_scatter(const int* __restrict__ src, const int* __restrict__ dst,
                                                 const int* __restrict__ row_ptr, int* __restrict__ cursor,
                                                 int* __restrict__ csr){
  int e = blockIdx.x*256 + threadIdx.x;
  if (e < N_EDGES){
    int d = dst[e];
    int pos = atomicAdd(&cursor[d], 1);
    csr[row_ptr[d] + pos] = src[e];
  }
}

// ---------------- small prep ----------------
__global__ __launch_bounds__(256) void k_pad_x(const float* __restrict__ x, float* __restrict__ xp){
  int i = blockIdx.x*256 + threadIdx.x;          // over N_NODES*16
  if (i < N_NODES*16){
    int n = i >> 4, k = i & 15;
    xp[i] = (k < IN_CH) ? x[n*IN_CH + k] : 0.0f;
  }
}

__global__ __launch_bounds__(256) void k_pad_w(const float* __restrict__ wl, const float* __restrict__ wr,
                                               float* __restrict__ wlp, float* __restrict__ wrp){
  int i = blockIdx.x*256 + threadIdx.x;          // 128*16
  if (i < HID*16){
    int n = i >> 4, k = i & 15;
    wlp[i] = (k < IN_CH) ? wl[n*IN_CH + k] : 0.0f;
    wrp[i] = (k < IN_CH) ? wr[n*IN_CH + k] : 0.0f;
  }
}

__global__ __launch_bounds__(256) void k_transpose_cw(const float* __restrict__ cw, float* __restrict__ cwT){
  int e = blockIdx.x*256 + threadIdx.x;          // 32*128*5 = 20480
  if (e < 32*HID*5){
    int o = e / 640, rem = e % 640;              // rem = c*5+s
    cwT[rem*32 + o] = cw[e];
  }
}

// ---------------- dual GEMM: TL = H@WL.T, TR = H@WR.T + b ----------------
// block: 256 thr, tile 64 rows x 64 cols, grid.y = 4 (TL half0, TL half1, TR half0, TR half1)
template<int K>
__global__ __launch_bounds__(256) void k_gemm_dual(const float* __restrict__ H,
    const float* __restrict__ WL, const float* __restrict__ WR, const float* __restrict__ bias,
    float* __restrict__ TL, float* __restrict__ TR){
  __shared__ float As[16][68];                   // As[k][row], pad 4 for banks/alignment
  __shared__ float Ws[16][68];                   // Ws[k][col]
  int r0 = blockIdx.x * 64;
  int ct = blockIdx.y;
  const float* W = (ct < 2) ? WL : WR;
  float* OUT = (ct < 2) ? TL : TR;
  int c0 = (ct & 1) * 64;
  int t = threadIdx.x;
  int tx = t & 15, ty = t >> 4;
  int lr = t >> 2;                               // 0..63
  int kq = (t & 3) * 4;                          // 0,4,8,12
  float acc[4][4] = {};
  for (int kt = 0; kt < K; kt += 16){
    float4 av = *(const float4*)&H[(r0 + lr)*K + kt + kq];
    float4 wv = *(const float4*)&W[(c0 + lr)*K + kt + kq];
    As[kq+0][lr] = av.x; As[kq+1][lr] = av.y; As[kq+2][lr] = av.z; As[kq+3][lr] = av.w;
    Ws[kq+0][lr] = wv.x; Ws[kq+1][lr] = wv.y; Ws[kq+2][lr] = wv.z; Ws[kq+3][lr] = wv.w;
    __syncthreads();
    #pragma unroll
    for (int k = 0; k < 16; ++k){
      float4 a = *(const float4*)&As[k][ty*4];
      float4 b = *(const float4*)&Ws[k][tx*4];
      float aa[4] = {a.x, a.y, a.z, a.w};
      float bb[4] = {b.x, b.y, b.z, b.w};
      #pragma unroll
      for (int i = 0; i < 4; ++i)
        #pragma unroll
        for (int j = 0; j < 4; ++j)
          acc[i][j] += aa[i]*bb[j];
    }
    __syncthreads();
  }
  #pragma unroll
  for (int i = 0; i < 4; ++i){
    int r = r0 + ty*4 + i;
    float4 o;
    o.x = acc[i][0]; o.y = acc[i][1]; o.z = acc[i][2]; o.w = acc[i][3];
    if (ct >= 2){
      int cb = c0 + tx*4;
      o.x += bias[cb+0]; o.y += bias[cb+1]; o.z += bias[cb+2]; o.w += bias[cb+3];
    }
    *(float4*)&OUT[r*HID + c0 + tx*4] = o;
  }
}

// ---------------- gather-combine: TR[i] = relu(deg_inv[i]*sum_{j in N(i)} TL[j] + TR[i]) ----------------
__global__ __launch_bounds__(128) void k_combine(const float* __restrict__ TL, float* __restrict__ TR,
    const int* __restrict__ row_ptr, const int* __restrict__ csr, const float* __restrict__ deg_inv){
  int i = blockIdx.x;
  int c = threadIdx.x;
  __shared__ int se[128];
  int s = row_ptr[i], e = row_ptr[i+1];
  float acc = 0.0f;
  for (int base = s; base < e; base += 128){
    int n = e - base; if (n > 128) n = 128;
    __syncthreads();
    if (c < n) se[c] = csr[base + c];
    __syncthreads();
    for (int j = 0; j < n; ++j) acc += TL[se[j]*HID + c];
  }
  float v = acc * deg_inv[i] + TR[i*HID + c];
  TR[i*HID + c] = fmaxf(v, 0.0f);
}

// ---------------- sort-pool: per graph, top-30 by last channel (desc, tie -> lower idx) ----------------
__global__ __launch_bounds__(1024) void k_sortpool(const float* __restrict__ H3, int* __restrict__ sel){
  int g = blockIdx.x, t = threadIdx.x;
  __shared__ unsigned long long key[N_PER];
  __shared__ unsigned long long wred[16];
  float v = H3[(g*N_PER + t)*HID + (HID-1)];     // post-relu, v >= 0 so float bits are monotone
  key[t] = (((unsigned long long)__float_as_uint(v)) << 10) | (unsigned long long)(N_PER-1 - t);
  __syncthreads();
  for (int r = 0; r < KSP; ++r){
    unsigned long long k = key[t];
    #pragma unroll
    for (int ofs = 32; ofs > 0; ofs >>= 1){
      unsigned long long o2 = __shfl_down(k, ofs, 64);
      if (o2 > k) k = o2;
    }
    if ((t & 63) == 0) wred[t >> 6] = k;
    __syncthreads();
    if (t == 0){
      unsigned long long m = wred[0];
      #pragma unroll
      for (int j = 1; j < 16; ++j) if (wred[j] > m) m = wred[j];
      int idx = (N_PER-1) - (int)(m & 1023ULL);
      sel[g*KSP + r] = idx;
      key[idx] = 0ULL;                           // remove from candidates
    }
    __syncthreads();
  }
}

// ---------------- head: gather top-30 -> conv1d(k=5) -> relu -> lin1 -> relu -> lin2 ----------------
__global__ __launch_bounds__(256) void k_head(const float* __restrict__ H3, const int* __restrict__ sel,
    const float* __restrict__ cwT, const float* __restrict__ cb,
    const float* __restrict__ l1w, const float* __restrict__ l1b,
    const float* __restrict__ l2w, const float* __restrict__ l2b,
    float* __restrict__ out){
  __shared__ __align__(16) float toplds[KSP*HID];   // 15 KB, [t][c]
  __shared__ float ypart[8][832];                   // 26 KB
  __shared__ __align__(16) float yv[832];
  __shared__ float zv[HID];
  int g = blockIdx.x, t = threadIdx.x;
  for (int e = t; e < KSP*HID; e += 256){
    int tt = e >> 7, c = e & 127;
    toplds[e] = H3[(g*N_PER + sel[g*KSP + tt])*HID + c];
  }
  __syncthreads();
  // conv: thread = (o = t&31, c-chunk = t>>5 of 16 channels); acc over 26 positions
  int o = t & 31, cch = t >> 5;
  float acc[26];
  #pragma unroll
  for (int th = 0; th < 26; ++th) acc[th] = 0.0f;
  for (int c = cch*16; c < cch*16 + 16; ++c){
    float tcol[KSP];
    #pragma unroll
    for (int tt = 0; tt < KSP; ++tt) tcol[tt] = toplds[tt*HID + c];
    float w5[5];
    #pragma unroll
    for (int s = 0; s < 5; ++s) w5[s] = cwT[(c*5 + s)*32 + o];
    #pragma unroll
    for (int th = 0; th < 26; ++th){
      float a2 = acc[th];
      #pragma unroll
      for (int s = 0; s < 5; ++s) a2 += tcol[th + s]*w5[s];
      acc[th] = a2;
    }
  }
  #pragma unroll
  for (int th = 0; th < 26; ++th) ypart[cch][o*26 + th] = acc[th];
  __syncthreads();
  for (int idx = t; idx < 832; idx += 256){
    float s2 = 0.0f;
    #pragma unroll
    for (int j = 0; j < 8; ++j) s2 += ypart[j][idx];
    yv[idx] = fmaxf(s2 + cb[idx / 26], 0.0f);       // flat order = o*26 + th
  }
  __syncthreads();
  if (t < HID){
    float a3 = l1b[t];
    const float4* wr4 = (const float4*)&l1w[t*832];
    const float4* yr4 = (const float4*)yv;
    #pragma unroll 4
    for (int k = 0; k < 208; ++k){
      float4 wv = wr4[k]; float4 yq = yr4[k];
      a3 += wv.x*yq.x + wv.y*yq.y + wv.z*yq.z + wv.w*yq.w;
    }
    zv[t] = fmaxf(a3, 0.0f);
  }
  __syncthreads();
  if (t < OUT_DIM){
    float a4 = l2b[t];
    for (int j = 0; j < HID; ++j) a4 += zv[j]*l2w[t*HID + j];
    out[g*OUT_DIM + t] = a4;
  }
}

extern "C" void kernel_launch(void* const* d_in, const int* in_sizes, int n_in,
                              void* d_out, int out_size, void* d_ws, size_t ws_size,
                              hipStream_t stream){
  const float* x   = (const float*)d_in[0];
  const int*   ei  = (const int*)d_in[1];
  const float* wl1 = (const float*)d_in[3];
  const float* b1  = (const float*)d_in[4];
  const float* wr1 = (const float*)d_in[5];
  const float* wl2 = (const float*)d_in[6];
  const float* b2  = (const float*)d_in[7];
  const float* wr2 = (const float*)d_in[8];
  const float* wl3 = (const float*)d_in[9];
  const float* b3  = (const float*)d_in[10];
  const float* wr3 = (const float*)d_in[11];
  const float* cw  = (const float*)d_in[12];
  const float* cb  = (const float*)d_in[13];
  const float* l1w = (const float*)d_in[14];
  const float* l1b = (const float*)d_in[15];
  const float* l2w = (const float*)d_in[16];
  const float* l2b = (const float*)d_in[17];
  float* out = (float*)d_out;
  const int* esrc = ei;
  const int* edst = ei + N_EDGES;

  char* p = (char*)d_ws;
  auto alloc = [&](size_t bytes)->char*{ char* r = p; p += (bytes + 255) & ~(size_t)255; return r; };
  int*   deg     = (int*)alloc((size_t)N_NODES*4);
  int*   cursor  = (int*)alloc((size_t)N_NODES*4);
  int*   row_ptr = (int*)alloc((size_t)(N_NODES+1)*4);
  int*   bsum    = (int*)alloc(512*4);
  float* dinv    = (float*)alloc((size_t)N_NODES*4);
  int*   csr     = (int*)alloc((size_t)N_EDGES*4);
  int*   sel     = (int*)alloc((size_t)NGRAPH*KSP*4);
  float* xp      = (float*)alloc((size_t)N_NODES*16*4);
  float* wl1p    = (float*)alloc((size_t)HID*16*4);
  float* wr1p    = (float*)alloc((size_t)HID*16*4);
  float* cwT     = (float*)alloc((size_t)32*HID*5*4);
  float* bufA    = (float*)alloc((size_t)N_NODES*HID*4);   // TL scratch
  float* bufB    = (float*)alloc((size_t)N_NODES*HID*4);   // h1 / h3
  float* bufC    = (float*)alloc((size_t)N_NODES*HID*4);   // h2

  hipMemsetAsync(deg, 0, (size_t)N_NODES*4, stream);
  hipMemsetAsync(cursor, 0, (size_t)N_NODES*4, stream);
  k_count_deg<<<N_EDGES/256, 256, 0, stream>>>(edst, deg);
  k_scan1<<<N_NODES/256, 256, 0, stream>>>(deg, row_ptr, dinv, bsum);
  k_scan2<<<1, 512, 0, stream>>>(bsum, row_ptr);
  k_scan3<<<N_NODES/256, 256, 0, stream>>>(row_ptr, bsum);
  k_scatter<<<N_EDGES/256, 256, 0, stream>>>(esrc, edst, row_ptr, cursor, csr);
  k_pad_x<<<(N_NODES*16)/256, 256, 0, stream>>>(x, xp);
  k_pad_w<<<(HID*16 + 255)/256, 256, 0, stream>>>(wl1, wr1, wl1p, wr1p);
  k_transpose_cw<<<(32*HID*5 + 255)/256, 256, 0, stream>>>(cw, cwT);

  dim3 gg(N_NODES/64, 4);
  // layer 1 (padded K=16)
  k_gemm_dual<16><<<gg, 256, 0, stream>>>(xp, wl1p, wr1p, b1, bufA, bufB);
  k_combine<<<N_NODES, 128, 0, stream>>>(bufA, bufB, row_ptr, csr, dinv);
  // layer 2
  k_gemm_dual<128><<<gg, 256, 0, stream>>>(bufB, wl2, wr2, b2, bufA, bufC);
  k_combine<<<N_NODES, 128, 0, stream>>>(bufA, bufC, row_ptr, csr, dinv);
  // layer 3
  k_gemm_dual<128><<<gg, 256, 0, stream>>>(bufC, wl3, wr3, b3, bufA, bufB);
  k_combine<<<N_NODES, 128, 0, stream>>>(bufA, bufB, row_ptr, csr, dinv);

  k_sortpool<<<NGRAPH, 1024, 0, stream>>>(bufB, sel);
  k_head<<<NGRAPH, 256, 0, stream>>>(bufB, sel, cwT, cb, l1w, l1b, l2w, l2b, out);
}

// Round 2
// 811.128 us; speedup vs baseline: 1.1073x; 1.1073x over previous
//
#include <hip/hip_runtime.h>
#include <hip/hip_bf16.h>

#define N_NODES 131072
#define N_PER   1024
#define NGRAPH  128
#define N_EDGES 2097152
#define KSP     30
#define HID     128
#define IN_CH   14
#define OUT_DIM 4

typedef __attribute__((ext_vector_type(8))) short v8s;   // 8 bf16 (4 VGPR)
typedef __attribute__((ext_vector_type(4))) float v4f;   // MFMA acc

__device__ inline ushort bfr(float x){            // fp32 -> bf16 RNE (bits)
  uint u = __float_as_uint(x);
  u += 0x7fffu + ((u >> 16) & 1u);
  return (ushort)(u >> 16);
}
__device__ inline float bfu(ushort h){ return __uint_as_float(((uint)h) << 16); }

// ---------------- CSR build ----------------
__global__ __launch_bounds__(256) void k_count_deg(const int* __restrict__ dst, int* __restrict__ deg){
  int e = blockIdx.x*256 + threadIdx.x;
  if (e < N_EDGES) atomicAdd(&deg[dst[e]], 1);
}

__global__ __launch_bounds__(256) void k_scan1(const int* __restrict__ deg, int* __restrict__ row_ptr,
                                               float* __restrict__ deg_inv, int* __restrict__ bsum){
  __shared__ int sh[256];
  int t = threadIdx.x;
  int e = blockIdx.x*256 + t;
  int d = deg[e];
  sh[t] = d; __syncthreads();
  for (int ofs=1; ofs<256; ofs<<=1){
    int v = sh[t];
    int add = (t>=ofs) ? sh[t-ofs] : 0;
    __syncthreads();
    sh[t] = v + add;
    __syncthreads();
  }
  row_ptr[e] = sh[t] - d;
  deg_inv[e] = d > 0 ? 1.0f/(float)d : 0.0f;
  if (t==255) bsum[blockIdx.x] = sh[255];
}

__global__ __launch_bounds__(512) void k_scan2(int* __restrict__ bsum, int* __restrict__ row_ptr){
  __shared__ int sh[512];
  int t = threadIdx.x;
  int v0 = bsum[t];
  sh[t] = v0; __syncthreads();
  for (int ofs=1; ofs<512; ofs<<=1){
    int v = sh[t];
    int add = (t>=ofs) ? sh[t-ofs] : 0;
    __syncthreads();
    sh[t] = v + add;
    __syncthreads();
  }
  bsum[t] = sh[t] - v0;
  if (t==511) row_ptr[N_NODES] = sh[511];
}

__global__ __launch_bounds__(256) void k_scan3(int* __restrict__ row_ptr, const int* __restrict__ bsum){
  int e = blockIdx.x*256 + threadIdx.x;
  row_ptr[e] += bsum[blockIdx.x];
}

__global__ __launch_bounds__(256) void k_scatter(const int* __restrict__ src, const int* __restrict__ dst,
                                                 const int* __restrict__ row_ptr, int* __restrict__ cursor,
                                                 int* __restrict__ csr){
  int e = blockIdx.x*256 + threadIdx.x;
  if (e < N_EDGES){
    int d = dst[e];
    int pos = atomicAdd(&cursor[d], 1);
    csr[row_ptr[d] + pos] = src[e];
  }
}

// ---------------- prep: hi/lo splits ----------------
__global__ __launch_bounds__(256) void k_splitx(const float* __restrict__ x,
                                                ushort* __restrict__ xhi, ushort* __restrict__ xlo){
  int i = blockIdx.x*256 + threadIdx.x;          // N_NODES*32
  int n = i >> 5, k = i & 31;
  float v = (k < IN_CH) ? x[n*IN_CH + k] : 0.0f;
  ushort hi = bfr(v);
  xhi[i] = hi;
  xlo[i] = bfr(v - bfu(hi));
}

__global__ __launch_bounds__(256) void k_splitw(const float* __restrict__ wl, const float* __restrict__ wr,
                                                ushort* __restrict__ whi, ushort* __restrict__ wlo,
                                                int K, int kin){
  int i = blockIdx.x*256 + threadIdx.x;          // 256*K
  if (i >= 256*K) return;
  int c = i / K, k = i - c*K;
  float v = 0.0f;
  if (k < kin) v = (c < 128) ? wl[c*kin + k] : wr[(c-128)*kin + k];
  ushort hi = bfr(v);
  whi[i] = hi;
  wlo[i] = bfr(v - bfu(hi));
}

__global__ __launch_bounds__(256) void k_transpose_cw(const float* __restrict__ cw, float* __restrict__ cwT){
  int e = blockIdx.x*256 + threadIdx.x;          // 32*128*5
  if (e < 32*HID*5){
    int o = e / 640, rem = e % 640;
    cwT[rem*32 + o] = cw[e];
  }
}

// ---------------- bf16x2 MFMA GEMM: T[r][0:128]=H@WL.T, T[r][128:256]=H@WR.T (+bias in epilogue) ----
// block 256 thr (4 waves). wave handles 32 rows x 256 cols. K = KT*32. No LDS, no barriers:
// a-frags direct from global (16 rows x 64B lines, coalesced); b-frags from L1 (W is ~128 KB).
template<int KT>
__global__ __launch_bounds__(256, 2) void k_gemm_bb(
    const ushort* __restrict__ Hhi, const ushort* __restrict__ Hlo,
    const ushort* __restrict__ Whi, const ushort* __restrict__ Wlo,
    const float* __restrict__ bias,
    float* __restrict__ TL, float* __restrict__ TR){
  constexpr int K = KT*32;
  const int t = threadIdx.x;
  const int w = t >> 6, l = t & 63;
  const int q = l >> 4, m = l & 15;
  const int r0 = blockIdx.x*128 + w*32;
  v4f acc[2][16];
  #pragma unroll
  for (int a = 0; a < 2; ++a)
    #pragma unroll
    for (int b = 0; b < 16; ++b) acc[a][b] = (v4f){0.f,0.f,0.f,0.f};
  #pragma unroll
  for (int kc = 0; kc < KT; ++kc){
    const int kb = kc*32 + q*8;
    v8s a0h = *(const v8s*)(Hhi + (r0 +      m)*K + kb);
    v8s a0l = *(const v8s*)(Hlo + (r0 +      m)*K + kb);
    v8s a1h = *(const v8s*)(Hhi + (r0 + 16 + m)*K + kb);
    v8s a1l = *(const v8s*)(Hlo + (r0 + 16 + m)*K + kb);
    #pragma unroll
    for (int tc = 0; tc < 16; ++tc){
      v8s bh = *(const v8s*)(Whi + (tc*16 + m)*K + kb);
      v8s bl = *(const v8s*)(Wlo + (tc*16 + m)*K + kb);
      acc[0][tc] = __builtin_amdgcn_mfma_f32_16x16x32_bf16(a0h, bh, acc[0][tc], 0, 0, 0);
      acc[0][tc] = __builtin_amdgcn_mfma_f32_16x16x32_bf16(a0l, bh, acc[0][tc], 0, 0, 0);
      acc[0][tc] = __builtin_amdgcn_mfma_f32_16x16x32_bf16(a0h, bl, acc[0][tc], 0, 0, 0);
      acc[1][tc] = __builtin_amdgcn_mfma_f32_16x16x32_bf16(a1h, bh, acc[1][tc], 0, 0, 0);
      acc[1][tc] = __builtin_amdgcn_mfma_f32_16x16x32_bf16(a1l, bh, acc[1][tc], 0, 0, 0);
      acc[1][tc] = __builtin_amdgcn_mfma_f32_16x16x32_bf16(a1h, bl, acc[1][tc], 0, 0, 0);
    }
  }
  // epilogue: D[row = q*4+reg][col = lane&15] per 16x16 tile
  #pragma unroll
  for (int tc = 0; tc < 16; ++tc){
    float badd = (tc >= 8) ? bias[(tc-8)*16 + m] : 0.0f;
    float* OUT = (tc < 8) ? TL : TR;
    int oc = (tc & 7)*16 + m;
    #pragma unroll
    for (int rt = 0; rt < 2; ++rt){
      int rowb = r0 + rt*16 + q*4;
      #pragma unroll
      for (int r = 0; r < 4; ++r)
        OUT[(rowb + r)*HID + oc] = acc[rt][tc][r] + badd;
    }
  }
}

// ---------------- combine: h = relu(dinv*sum_nbr TL + TR); MODE0 -> bf16 hi/lo, MODE1 -> fp32 in TR --
template<int MODE>
__global__ __launch_bounds__(256) void k_combine2(
    const float4* __restrict__ TL4, float4* __restrict__ TR4,
    const int* __restrict__ row_ptr, const int* __restrict__ csr,
    const float* __restrict__ dinv,
    ushort* __restrict__ Hhi, ushort* __restrict__ Hlo){
  int t = threadIdx.x;
  int node = blockIdx.x*8 + (t >> 5);
  int lane = t & 31;                    // 32 lanes x float4 = 128 channels
  int s = row_ptr[node], e = row_ptr[node+1];
  float4 acc = make_float4(0.f, 0.f, 0.f, 0.f);
  int j = s;
  for (; j + 8 <= e; j += 8){
    int i0 = csr[j+0], i1 = csr[j+1], i2 = csr[j+2], i3 = csr[j+3];
    int i4 = csr[j+4], i5 = csr[j+5], i6 = csr[j+6], i7 = csr[j+7];
    float4 v0 = TL4[i0*32 + lane]; float4 v1 = TL4[i1*32 + lane];
    float4 v2 = TL4[i2*32 + lane]; float4 v3 = TL4[i3*32 + lane];
    float4 v4 = TL4[i4*32 + lane]; float4 v5 = TL4[i5*32 + lane];
    float4 v6 = TL4[i6*32 + lane]; float4 v7 = TL4[i7*32 + lane];
    acc.x += ((v0.x+v1.x)+(v2.x+v3.x)) + ((v4.x+v5.x)+(v6.x+v7.x));
    acc.y += ((v0.y+v1.y)+(v2.y+v3.y)) + ((v4.y+v5.y)+(v6.y+v7.y));
    acc.z += ((v0.z+v1.z)+(v2.z+v3.z)) + ((v4.z+v5.z)+(v6.z+v7.z));
    acc.w += ((v0.w+v1.w)+(v2.w+v3.w)) + ((v4.w+v5.w)+(v6.w+v7.w));
  }
  for (; j < e; ++j){
    float4 v = TL4[csr[j]*32 + lane];
    acc.x += v.x; acc.y += v.y; acc.z += v.z; acc.w += v.w;
  }
  float di = dinv[node];
  float4 tr = TR4[node*32 + lane];
  float4 h;
  h.x = fmaxf(fmaf(acc.x, di, tr.x), 0.f);
  h.y = fmaxf(fmaf(acc.y, di, tr.y), 0.f);
  h.z = fmaxf(fmaf(acc.z, di, tr.z), 0.f);
  h.w = fmaxf(fmaf(acc.w, di, tr.w), 0.f);
  if (MODE == 0){
    ushort4 hi, lo;
    hi.x = bfr(h.x); lo.x = bfr(h.x - bfu(hi.x));
    hi.y = bfr(h.y); lo.y = bfr(h.y - bfu(hi.y));
    hi.z = bfr(h.z); lo.z = bfr(h.z - bfu(hi.z));
    hi.w = bfr(h.w); lo.w = bfr(h.w - bfu(hi.w));
    *(ushort4*)&Hhi[node*HID + lane*4] = hi;
    *(ushort4*)&Hlo[node*HID + lane*4] = lo;
  } else {
    TR4[node*32 + lane] = h;           // in-place fp32 h3 (only own row -> no race)
  }
}

// ---------------- sort-pool ----------------
__global__ __launch_bounds__(1024) void k_sortpool(const float* __restrict__ H3, int* __restrict__ sel){
  int g = blockIdx.x, t = threadIdx.x;
  __shared__ unsigned long long key[N_PER];
  __shared__ unsigned long long wred[16];
  float v = H3[(g*N_PER + t)*HID + (HID-1)];
  key[t] = (((unsigned long long)__float_as_uint(v)) << 10) | (unsigned long long)(N_PER-1 - t);
  __syncthreads();
  for (int r = 0; r < KSP; ++r){
    unsigned long long k = key[t];
    #pragma unroll
    for (int ofs = 32; ofs > 0; ofs >>= 1){
      unsigned long long o2 = __shfl_down(k, ofs, 64);
      if (o2 > k) k = o2;
    }
    if ((t & 63) == 0) wred[t >> 6] = k;
    __syncthreads();
    if (t == 0){
      unsigned long long mm = wred[0];
      #pragma unroll
      for (int j = 1; j < 16; ++j) if (wred[j] > mm) mm = wred[j];
      int idx = (N_PER-1) - (int)(mm & 1023ULL);
      sel[g*KSP + r] = idx;
      key[idx] = 0ULL;
    }
    __syncthreads();
  }
}

// ---------------- head ----------------
__global__ __launch_bounds__(256) void k_head(const float* __restrict__ H3, const int* __restrict__ sel,
    const float* __restrict__ cwT, const float* __restrict__ cb,
    const float* __restrict__ l1w, const float* __restrict__ l1b,
    const float* __restrict__ l2w, const float* __restrict__ l2b,
    float* __restrict__ out){
  __shared__ __align__(16) float toplds[KSP*HID];
  __shared__ float ypart[8][832];
  __shared__ __align__(16) float yv[832];
  __shared__ float zv[HID];
  int g = blockIdx.x, t = threadIdx.x;
  for (int e = t; e < KSP*HID; e += 256){
    int tt = e >> 7, c = e & 127;
    toplds[e] = H3[(g*N_PER + sel[g*KSP + tt])*HID + c];
  }
  __syncthreads();
  int o = t & 31, cch = t >> 5;
  float acc[26];
  #pragma unroll
  for (int th = 0; th < 26; ++th) acc[th] = 0.0f;
  for (int c = cch*16; c < cch*16 + 16; ++c){
    float tcol[KSP];
    #pragma unroll
    for (int tt = 0; tt < KSP; ++tt) tcol[tt] = toplds[tt*HID + c];
    float w5[5];
    #pragma unroll
    for (int s = 0; s < 5; ++s) w5[s] = cwT[(c*5 + s)*32 + o];
    #pragma unroll
    for (int th = 0; th < 26; ++th){
      float a2 = acc[th];
      #pragma unroll
      for (int s = 0; s < 5; ++s) a2 += tcol[th + s]*w5[s];
      acc[th] = a2;
    }
  }
  #pragma unroll
  for (int th = 0; th < 26; ++th) ypart[cch][o*26 + th] = acc[th];
  __syncthreads();
  for (int idx = t; idx < 832; idx += 256){
    float s2 = 0.0f;
    #pragma unroll
    for (int j = 0; j < 8; ++j) s2 += ypart[j][idx];
    yv[idx] = fmaxf(s2 + cb[idx / 26], 0.0f);
  }
  __syncthreads();
  if (t < HID){
    float a3 = l1b[t];
    const float4* wr4 = (const float4*)&l1w[t*832];
    const float4* yr4 = (const float4*)yv;
    #pragma unroll 4
    for (int k = 0; k < 208; ++k){
      float4 wv = wr4[k]; float4 yq = yr4[k];
      a3 += wv.x*yq.x + wv.y*yq.y + wv.z*yq.z + wv.w*yq.w;
    }
    zv[t] = fmaxf(a3, 0.0f);
  }
  __syncthreads();
  if (t < OUT_DIM){
    float a4 = l2b[t];
    for (int j = 0; j < HID; ++j) a4 += zv[j]*l2w[t*HID + j];
    out[g*OUT_DIM + t] = a4;
  }
}

extern "C" void kernel_launch(void* const* d_in, const int* in_sizes, int n_in,
                              void* d_out, int out_size, void* d_ws, size_t ws_size,
                              hipStream_t stream){
  const float* x   = (const float*)d_in[0];
  const int*   ei  = (const int*)d_in[1];
  const float* wl1 = (const float*)d_in[3];
  const float* b1  = (const float*)d_in[4];
  const float* wr1 = (const float*)d_in[5];
  const float* wl2 = (const float*)d_in[6];
  const float* b2  = (const float*)d_in[7];
  const float* wr2 = (const float*)d_in[8];
  const float* wl3 = (const float*)d_in[9];
  const float* b3  = (const float*)d_in[10];
  const float* wr3 = (const float*)d_in[11];
  const float* cw  = (const float*)d_in[12];
  const float* cb  = (const float*)d_in[13];
  const float* l1w = (const float*)d_in[14];
  const float* l1b = (const float*)d_in[15];
  const float* l2w = (const float*)d_in[16];
  const float* l2b = (const float*)d_in[17];
  float* out = (float*)d_out;
  const int* esrc = ei;
  const int* edst = ei + N_EDGES;

  char* p = (char*)d_ws;
  auto alloc = [&](size_t bytes)->char*{ char* r = p; p += (bytes + 255) & ~(size_t)255; return r; };
  int*    deg     = (int*)alloc((size_t)N_NODES*4);
  int*    cursor  = (int*)alloc((size_t)N_NODES*4);
  int*    row_ptr = (int*)alloc((size_t)(N_NODES+1)*4);
  int*    bsum    = (int*)alloc(512*4);
  float*  dinv    = (float*)alloc((size_t)N_NODES*4);
  int*    csr     = (int*)alloc((size_t)N_EDGES*4);
  int*    sel     = (int*)alloc((size_t)NGRAPH*KSP*4);
  float*  cwT     = (float*)alloc((size_t)32*HID*5*4);
  ushort* xhi     = (ushort*)alloc((size_t)N_NODES*32*2);
  ushort* xlo     = (ushort*)alloc((size_t)N_NODES*32*2);
  ushort* w1hi    = (ushort*)alloc((size_t)256*32*2);
  ushort* w1lo    = (ushort*)alloc((size_t)256*32*2);
  ushort* w2hi    = (ushort*)alloc((size_t)256*128*2);
  ushort* w2lo    = (ushort*)alloc((size_t)256*128*2);
  ushort* w3hi    = (ushort*)alloc((size_t)256*128*2);
  ushort* w3lo    = (ushort*)alloc((size_t)256*128*2);
  float*  TL      = (float*)alloc((size_t)N_NODES*HID*4);
  float*  TR      = (float*)alloc((size_t)N_NODES*HID*4);
  ushort* hHi     = (ushort*)alloc((size_t)N_NODES*HID*2);
  ushort* hLo     = (ushort*)alloc((size_t)N_NODES*HID*2);

  hipMemsetAsync(deg, 0, (size_t)N_NODES*4, stream);
  hipMemsetAsync(cursor, 0, (size_t)N_NODES*4, stream);
  k_count_deg<<<N_EDGES/256, 256, 0, stream>>>(edst, deg);
  k_scan1<<<N_NODES/256, 256, 0, stream>>>(deg, row_ptr, dinv, bsum);
  k_scan2<<<1, 512, 0, stream>>>(bsum, row_ptr);
  k_scan3<<<N_NODES/256, 256, 0, stream>>>(row_ptr, bsum);
  k_scatter<<<N_EDGES/256, 256, 0, stream>>>(esrc, edst, row_ptr, cursor, csr);

  k_splitx<<<(N_NODES*32)/256, 256, 0, stream>>>(x, xhi, xlo);
  k_splitw<<<(256*32)/256, 256, 0, stream>>>(wl1, wr1, w1hi, w1lo, 32, IN_CH);
  k_splitw<<<(256*128)/256, 256, 0, stream>>>(wl2, wr2, w2hi, w2lo, 128, 128);
  k_splitw<<<(256*128)/256, 256, 0, stream>>>(wl3, wr3, w3hi, w3lo, 128, 128);
  k_transpose_cw<<<(32*HID*5 + 255)/256, 256, 0, stream>>>(cw, cwT);

  const int GB = N_NODES/128;      // 1024 gemm blocks
  const int CB = N_NODES/8;        // 16384 combine blocks

  // layer 1 (K padded 14->32)
  k_gemm_bb<1><<<GB, 256, 0, stream>>>(xhi, xlo, w1hi, w1lo, b1, TL, TR);
  k_combine2<0><<<CB, 256, 0, stream>>>((const float4*)TL, (float4*)TR, row_ptr, csr, dinv, hHi, hLo);
  // layer 2
  k_gemm_bb<4><<<GB, 256, 0, stream>>>(hHi, hLo, w2hi, w2lo, b2, TL, TR);
  k_combine2<0><<<CB, 256, 0, stream>>>((const float4*)TL, (float4*)TR, row_ptr, csr, dinv, hHi, hLo);
  // layer 3 -> fp32 h3 written in place into TR
  k_gemm_bb<4><<<GB, 256, 0, stream>>>(hHi, hLo, w3hi, w3lo, b3, TL, TR);
  k_combine2<1><<<CB, 256, 0, stream>>>((const float4*)TL, (float4*)TR, row_ptr, csr, dinv, nullptr, nullptr);

  k_sortpool<<<NGRAPH, 1024, 0, stream>>>(TR, sel);
  k_head<<<NGRAPH, 256, 0, stream>>>(TR, sel, cwT, cb, l1w, l1b, l2w, l2b, out);
}

// Round 5
// 723.847 us; speedup vs baseline: 1.2408x; 1.1206x over previous
//
#include <hip/hip_runtime.h>
#include <hip/hip_bf16.h>
#include <hip/hip_fp16.h>

#define N_NODES 131072
#define N_PER   1024
#define NGRAPH  128
#define N_EDGES 2097152
#define KSP     30
#define HID     128
#define IN_CH   14
#define OUT_DIM 4

typedef __attribute__((ext_vector_type(8))) short    v8s;
typedef __attribute__((ext_vector_type(8))) _Float16 v8h;
typedef __attribute__((ext_vector_type(4))) float    v4f;

__device__ inline v8h as_h(v8s s){ union { v8s s; v8h h; } u; u.s = s; return u.h; }

// fp32 -> f16 hi + f16 lo (lo pre-scaled by 2^12). hi never denormal.
#define LOSCALE 4096.0f
#define INV_LOSCALE (1.0f/4096.0f)
__device__ inline void f2split(float v, ushort& hi, ushort& lo){
  float av = fabsf(v);
  __half h = (av < 6.103515625e-05f) ? __ushort_as_half((ushort)0) : __float2half(v);
  hi = __half_as_ushort(h);
  lo = __half_as_ushort(__float2half((v - __half2float(h)) * LOSCALE));
}
__device__ inline float f2join(ushort hi, ushort lo){
  return __half2float(__ushort_as_half(hi)) + __half2float(__ushort_as_half(lo)) * INV_LOSCALE;
}

// ---------------- CSR build ----------------
__global__ __launch_bounds__(256) void k_count_deg(const int* __restrict__ dst, int* __restrict__ deg){
  int e = blockIdx.x*256 + threadIdx.x;
  if (e < N_EDGES) atomicAdd(&deg[dst[e]], 1);
}

__global__ __launch_bounds__(256) void k_scan1(const int* __restrict__ deg, int* __restrict__ row_ptr,
                                               float* __restrict__ deg_inv, int* __restrict__ bsum){
  __shared__ int sh[256];
  int t = threadIdx.x;
  int e = blockIdx.x*256 + t;
  int d = deg[e];
  sh[t] = d; __syncthreads();
  for (int ofs=1; ofs<256; ofs<<=1){
    int v = sh[t];
    int add = (t>=ofs) ? sh[t-ofs] : 0;
    __syncthreads();
    sh[t] = v + add;
    __syncthreads();
  }
  row_ptr[e] = sh[t] - d;
  deg_inv[e] = d > 0 ? 1.0f/(float)d : 0.0f;
  if (t==255) bsum[blockIdx.x] = sh[255];
}

__global__ __launch_bounds__(512) void k_scan2(int* __restrict__ bsum, int* __restrict__ row_ptr){
  __shared__ int sh[512];
  int t = threadIdx.x;
  int v0 = bsum[t];
  sh[t] = v0; __syncthreads();
  for (int ofs=1; ofs<512; ofs<<=1){
    int v = sh[t];
    int add = (t>=ofs) ? sh[t-ofs] : 0;
    __syncthreads();
    sh[t] = v + add;
    __syncthreads();
  }
  bsum[t] = sh[t] - v0;
  if (t==511) row_ptr[N_NODES] = sh[511];
}

__global__ __launch_bounds__(256) void k_scan3(int* __restrict__ row_ptr, const int* __restrict__ bsum){
  int e = blockIdx.x*256 + threadIdx.x;
  row_ptr[e] += bsum[blockIdx.x];
}

__global__ __launch_bounds__(256) void k_scatter(const int* __restrict__ src, const int* __restrict__ dst,
                                                 const int* __restrict__ row_ptr, int* __restrict__ cursor,
                                                 int* __restrict__ csr){
  int e = blockIdx.x*256 + threadIdx.x;
  if (e < N_EDGES){
    int d = dst[e];
    int pos = atomicAdd(&cursor[d], 1);
    csr[row_ptr[d] + pos] = src[e];
  }
}

// ---------------- prep: pack x / W into MFMA-fragment layouts (f16 hi/lo planes) ----------------
// frag index for row-major X[N][K] (K = KC*32): (n,k) -> ((n>>4)*KC + (k>>5))*512
//   + (((k&31)>>3)*16 + (n&15))*8 + (k&7)
__global__ __launch_bounds__(256) void k_pack_x(const float* __restrict__ x,
                                                ushort* __restrict__ xhi, ushort* __restrict__ xlo){
  int i = blockIdx.x*256 + threadIdx.x;          // N_NODES*32
  int n = i >> 5, k = i & 31;
  float v = (k < IN_CH) ? x[n*IN_CH + k] : 0.0f;
  int dst = (n >> 4)*512 + ((k >> 3)*16 + (n & 15))*8 + (k & 7);
  ushort hi, lo; f2split(v, hi, lo);
  xhi[dst] = hi; xlo[dst] = lo;
}

__global__ __launch_bounds__(256) void k_pack_w(const float* __restrict__ wl, const float* __restrict__ wr,
    ushort* __restrict__ wlh, ushort* __restrict__ wll,
    ushort* __restrict__ wrh, ushort* __restrict__ wrl, int KC, int kin){
  int i = blockIdx.x*256 + threadIdx.x;
  int Kp = KC*32;
  if (i >= 256*Kp) return;
  int which = i / (128*Kp);
  int r = (i / Kp) & 127;
  int k = i % Kp;
  const float* w = which ? wr : wl;
  float v = (k < kin) ? w[r*kin + k] : 0.0f;
  ushort hi, lo; f2split(v, hi, lo);
  int dst = ((r >> 4)*KC + (k >> 5))*512 + ((((k & 31) >> 3))*16 + (r & 15))*8 + (k & 7);
  if (which){ wrh[dst] = hi; wrl[dst] = lo; }
  else      { wlh[dst] = hi; wll[dst] = lo; }
}

__global__ __launch_bounds__(256) void k_transpose_cw(const float* __restrict__ cw, float* __restrict__ cwT){
  int e = blockIdx.x*256 + threadIdx.x;          // 32*128*5
  if (e < 32*HID*5){
    int o = e / 640, rem = e % 640;
    cwT[rem*32 + o] = cw[e];
  }
}

// ---------------- gather: M[i] = mean_{j->i} H[j] (frag layout in/out) ----------------
// grid = NGRAPH*(2*KC); block = (graph g, 16-channel pass). 1024 thr. LDS-staged fp32.
// DETERMINISM: int64 fixed-point accumulation (order-independent under csr permutation).
#define FXS 16777216.0f
__global__ __launch_bounds__(1024) void k_gather(
    const ushort* __restrict__ Hhi, const ushort* __restrict__ Hlo,
    ushort* __restrict__ Mhi, ushort* __restrict__ Mlo,
    const int* __restrict__ row_ptr, const int* __restrict__ csr,
    const float* __restrict__ dinv, int KC){
  __shared__ float lds[N_PER*20];                // 80 KB
  int P = KC*2;
  int g = blockIdx.x / P, p = blockIdx.x % P;
  int kc = p >> 1, half = p & 1;
  int t = threadIdx.x;
  for (int it = t; it < 16384; it += 1024){
    int Tl = it >> 8, e = it & 255;
    int idx = (((g*64 + Tl)*KC + kc) << 9) + (half << 8) + e;
    float v = f2join(Hhi[idx], Hlo[idx]);
    int l = e >> 3, j = e & 7;
    int m = l & 15, qh = l >> 4;
    lds[(Tl*16 + m)*20 + qh*8 + j] = v;
  }
  __syncthreads();
  int o2 = t & 1, ns = t >> 1;
  #pragma unroll
  for (int rep = 0; rep < 2; ++rep){
    int n = ns + rep*512;
    int node = g*N_PER + n;
    int s = row_ptr[node], e = row_ptr[node+1];
    long long a0=0,a1=0,a2=0,a3=0,a4=0,a5=0,a6=0,a7=0;
    int j2 = s;
    for (; j2 + 2 <= e; j2 += 2){
      int la = csr[j2] & (N_PER-1);
      int lb = csr[j2+1] & (N_PER-1);
      const float4* ra = (const float4*)&lds[la*20 + o2*8];
      const float4* rb = (const float4*)&lds[lb*20 + o2*8];
      float4 x0 = ra[0], x1 = ra[1], y0 = rb[0], y1 = rb[1];
      a0 += (long long)__float2int_rn(x0.x*FXS) + (long long)__float2int_rn(y0.x*FXS);
      a1 += (long long)__float2int_rn(x0.y*FXS) + (long long)__float2int_rn(y0.y*FXS);
      a2 += (long long)__float2int_rn(x0.z*FXS) + (long long)__float2int_rn(y0.z*FXS);
      a3 += (long long)__float2int_rn(x0.w*FXS) + (long long)__float2int_rn(y0.w*FXS);
      a4 += (long long)__float2int_rn(x1.x*FXS) + (long long)__float2int_rn(y1.x*FXS);
      a5 += (long long)__float2int_rn(x1.y*FXS) + (long long)__float2int_rn(y1.y*FXS);
      a6 += (long long)__float2int_rn(x1.z*FXS) + (long long)__float2int_rn(y1.z*FXS);
      a7 += (long long)__float2int_rn(x1.w*FXS) + (long long)__float2int_rn(y1.w*FXS);
    }
    if (j2 < e){
      int la = csr[j2] & (N_PER-1);
      const float4* ra = (const float4*)&lds[la*20 + o2*8];
      float4 x0 = ra[0], x1 = ra[1];
      a0 += (long long)__float2int_rn(x0.x*FXS);
      a1 += (long long)__float2int_rn(x0.y*FXS);
      a2 += (long long)__float2int_rn(x0.z*FXS);
      a3 += (long long)__float2int_rn(x0.w*FXS);
      a4 += (long long)__float2int_rn(x1.x*FXS);
      a5 += (long long)__float2int_rn(x1.y*FXS);
      a6 += (long long)__float2int_rn(x1.z*FXS);
      a7 += (long long)__float2int_rn(x1.w*FXS);
    }
    float di = dinv[node] * (1.0f/FXS);
    float mv[8] = {(float)a0*di,(float)a1*di,(float)a2*di,(float)a3*di,
                   (float)a4*di,(float)a5*di,(float)a6*di,(float)a7*di};
    int q = half*2 + o2;
    int base = (((g*64 + (n >> 4))*KC + kc) << 9) + (q*16 + (n & 15))*8;
    ushort hs[8], ls[8];
    #pragma unroll
    for (int ii = 0; ii < 8; ++ii) f2split(mv[ii], hs[ii], ls[ii]);
    *(ushort4*)&Mhi[base]   = make_ushort4(hs[0],hs[1],hs[2],hs[3]);
    *(ushort4*)&Mhi[base+4] = make_ushort4(hs[4],hs[5],hs[6],hs[7]);
    *(ushort4*)&Mlo[base]   = make_ushort4(ls[0],ls[1],ls[2],ls[3]);
    *(ushort4*)&Mlo[base+4] = make_ushort4(ls[4],ls[5],ls[6],ls[7]);
  }
}

// ---------------- GEMM: h = relu(M@Wl + H@Wr + b), fp16x2 dual-accumulator ----------------
template<int KCI, int MODE>   // MODE0: write f16 hi/lo planes (KC_out=4). MODE1: fp32 row-major.
__global__ __launch_bounds__(256) void k_gemm(
    const ushort* __restrict__ Ah1, const ushort* __restrict__ Al1,
    const ushort* __restrict__ Ah2, const ushort* __restrict__ Al2,
    const ushort* __restrict__ wlh, const ushort* __restrict__ wll,
    const ushort* __restrict__ wrh, const ushort* __restrict__ wrl,
    const float* __restrict__ bias, ushort* Hho, ushort* Hlo2, float* Fout){
  int t = threadIdx.x, w = t >> 6, l = t & 63;
  int q = l >> 4, m = l & 15;
  int t0 = blockIdx.x*8 + w*2;                   // first of 2 row-tiles
  v4f acc1[2][8], acc2[2][8];
  #pragma unroll
  for (int a = 0; a < 2; ++a)
    #pragma unroll
    for (int b = 0; b < 8; ++b){ acc1[a][b] = (v4f){0.f,0.f,0.f,0.f}; acc2[a][b] = (v4f){0.f,0.f,0.f,0.f}; }
  #pragma unroll
  for (int kc = 0; kc < KCI; ++kc){
    #pragma unroll
    for (int src = 0; src < 2; ++src){
      const ushort* AH = src ? Ah2 : Ah1;
      const ushort* AL = src ? Al2 : Al1;
      const ushort* WH = src ? wrh : wlh;
      const ushort* WL = src ? wrl : wll;
      v8h ah[2], al[2];
      #pragma unroll
      for (int rt = 0; rt < 2; ++rt){
        int aoff = (((t0+rt)*KCI + kc) << 9) + l*8;
        ah[rt] = as_h(*(const v8s*)(AH + aoff));
        al[rt] = as_h(*(const v8s*)(AL + aoff));
      }
      #pragma unroll
      for (int ct = 0; ct < 8; ++ct){
        int boff = ((ct*KCI + kc) << 9) + l*8;
        v8h bh = as_h(*(const v8s*)(WH + boff));
        v8h bl = as_h(*(const v8s*)(WL + boff));
        #pragma unroll
        for (int rt = 0; rt < 2; ++rt){
          acc1[rt][ct] = __builtin_amdgcn_mfma_f32_16x16x32_f16(ah[rt], bh, acc1[rt][ct], 0, 0, 0);
          acc2[rt][ct] = __builtin_amdgcn_mfma_f32_16x16x32_f16(al[rt], bh, acc2[rt][ct], 0, 0, 0);
          acc2[rt][ct] = __builtin_amdgcn_mfma_f32_16x16x32_f16(ah[rt], bl, acc2[rt][ct], 0, 0, 0);
        }
      }
    }
  }
  // epilogue: D row (in tile) = q*4+r, col = ct*16+m
  #pragma unroll
  for (int ct = 0; ct < 8; ++ct){
    float badd = bias[ct*16 + m];
    #pragma unroll
    for (int rt = 0; rt < 2; ++rt){
      #pragma unroll
      for (int r = 0; r < 4; ++r){
        float v = fmaxf(acc1[rt][ct][r] + acc2[rt][ct][r]*INV_LOSCALE + badd, 0.0f);
        if (MODE == 0){
          int kc2 = ct >> 1;
          int lane2 = ((ct & 1)*2 + (m >> 3))*16 + q*4 + r;
          int didx = (((t0+rt)*4 + kc2) << 9) + lane2*8 + (m & 7);
          ushort hi, lo; f2split(v, hi, lo);
          Hho[didx] = hi; Hlo2[didx] = lo;
        } else {
          Fout[((t0+rt)*16 + q*4 + r)*HID + ct*16 + m] = v;
        }
      }
    }
  }
}

// ---------------- sort-pool ----------------
__global__ __launch_bounds__(1024) void k_sortpool(const float* __restrict__ H3, int* __restrict__ sel){
  int g = blockIdx.x, t = threadIdx.x;
  __shared__ unsigned long long key[N_PER];
  __shared__ unsigned long long wred[16];
  float v = H3[(g*N_PER + t)*HID + (HID-1)];
  key[t] = (((unsigned long long)__float_as_uint(v)) << 10) | (unsigned long long)(N_PER-1 - t);
  __syncthreads();
  for (int r = 0; r < KSP; ++r){
    unsigned long long k = key[t];
    #pragma unroll
    for (int ofs = 32; ofs > 0; ofs >>= 1){
      unsigned long long o2 = __shfl_down(k, ofs, 64);
      if (o2 > k) k = o2;
    }
    if ((t & 63) == 0) wred[t >> 6] = k;
    __syncthreads();
    if (t == 0){
      unsigned long long mm = wred[0];
      #pragma unroll
      for (int j = 1; j < 16; ++j) if (wred[j] > mm) mm = wred[j];
      int idx = (N_PER-1) - (int)(mm & 1023ULL);
      sel[g*KSP + r] = idx;
      key[idx] = 0ULL;
    }
    __syncthreads();
  }
}

// ---------------- head ----------------
__global__ __launch_bounds__(256) void k_head(const float* __restrict__ H3, const int* __restrict__ sel,
    const float* __restrict__ cwT, const float* __restrict__ cb,
    const float* __restrict__ l1w, const float* __restrict__ l1b,
    const float* __restrict__ l2w, const float* __restrict__ l2b,
    float* __restrict__ out){
  __shared__ __align__(16) float toplds[KSP*HID];
  __shared__ float ypart[8][832];
  __shared__ __align__(16) float yv[832];
  __shared__ float zv[HID];
  int g = blockIdx.x, t = threadIdx.x;
  for (int e = t; e < KSP*HID; e += 256){
    int tt = e >> 7, c = e & 127;
    toplds[e] = H3[(g*N_PER + sel[g*KSP + tt])*HID + c];
  }
  __syncthreads();
  int o = t & 31, cch = t >> 5;
  float acc[26];
  #pragma unroll
  for (int th = 0; th < 26; ++th) acc[th] = 0.0f;
  for (int c = cch*16; c < cch*16 + 16; ++c){
    float tcol[KSP];
    #pragma unroll
    for (int tt = 0; tt < KSP; ++tt) tcol[tt] = toplds[tt*HID + c];
    float w5[5];
    #pragma unroll
    for (int s = 0; s < 5; ++s) w5[s] = cwT[(c*5 + s)*32 + o];
    #pragma unroll
    for (int th = 0; th < 26; ++th){
      float a2 = acc[th];
      #pragma unroll
      for (int s = 0; s < 5; ++s) a2 += tcol[th + s]*w5[s];
      acc[th] = a2;
    }
  }
  #pragma unroll
  for (int th = 0; th < 26; ++th) ypart[cch][o*26 + th] = acc[th];
  __syncthreads();
  for (int idx = t; idx < 832; idx += 256){
    float s2 = 0.0f;
    #pragma unroll
    for (int j = 0; j < 8; ++j) s2 += ypart[j][idx];
    yv[idx] = fmaxf(s2 + cb[idx / 26], 0.0f);
  }
  __syncthreads();
  if (t < HID){
    float a3 = l1b[t];
    const float4* wr4 = (const float4*)&l1w[t*832];
    const float4* yr4 = (const float4*)yv;
    #pragma unroll 4
    for (int k = 0; k < 208; ++k){
      float4 wv = wr4[k]; float4 yq = yr4[k];
      a3 += wv.x*yq.x + wv.y*yq.y + wv.z*yq.z + wv.w*yq.w;
    }
    zv[t] = fmaxf(a3, 0.0f);
  }
  __syncthreads();
  if (t < OUT_DIM){
    float a4 = l2b[t];
    for (int j = 0; j < HID; ++j) a4 += zv[j]*l2w[t*HID + j];
    out[g*OUT_DIM + t] = a4;
  }
}

extern "C" void kernel_launch(void* const* d_in, const int* in_sizes, int n_in,
                              void* d_out, int out_size, void* d_ws, size_t ws_size,
                              hipStream_t stream){
  const float* x   = (const float*)d_in[0];
  const int*   ei  = (const int*)d_in[1];
  const float* wl1 = (const float*)d_in[3];
  const float* b1  = (const float*)d_in[4];
  const float* wr1 = (const float*)d_in[5];
  const float* wl2 = (const float*)d_in[6];
  const float* b2  = (const float*)d_in[7];
  const float* wr2 = (const float*)d_in[8];
  const float* wl3 = (const float*)d_in[9];
  const float* b3  = (const float*)d_in[10];
  const float* wr3 = (const float*)d_in[11];
  const float* cw  = (const float*)d_in[12];
  const float* cb  = (const float*)d_in[13];
  const float* l1w = (const float*)d_in[14];
  const float* l1b = (const float*)d_in[15];
  const float* l2w = (const float*)d_in[16];
  const float* l2b = (const float*)d_in[17];
  float* out = (float*)d_out;
  const int* esrc = ei;
  const int* edst = ei + N_EDGES;

  char* p = (char*)d_ws;
  auto alloc = [&](size_t bytes)->char*{ char* r = p; p += (bytes + 255) & ~(size_t)255; return r; };
  int*    deg     = (int*)alloc((size_t)N_NODES*4);
  int*    cursor  = (int*)alloc((size_t)N_NODES*4);
  int*    row_ptr = (int*)alloc((size_t)(N_NODES+1)*4);
  int*    bsum    = (int*)alloc(512*4);
  float*  dinv    = (float*)alloc((size_t)N_NODES*4);
  int*    csr     = (int*)alloc((size_t)N_EDGES*4);
  int*    sel     = (int*)alloc((size_t)NGRAPH*KSP*4);
  float*  cwT     = (float*)alloc((size_t)32*HID*5*4);
  ushort* Xhi     = (ushort*)alloc((size_t)N_NODES*32*2);   // 8.4 MB
  ushort* Xlo     = (ushort*)alloc((size_t)N_NODES*32*2);
  ushort* Mhi     = (ushort*)alloc((size_t)N_NODES*HID*2);  // 33.5 MB
  ushort* Mlo     = (ushort*)alloc((size_t)N_NODES*HID*2);
  ushort* Hhi     = (ushort*)alloc((size_t)N_NODES*HID*2);
  ushort* Hlo     = (ushort*)alloc((size_t)N_NODES*HID*2);
  float*  H3      = (float*)alloc((size_t)N_NODES*HID*4);   // 67 MB
  ushort* w1lh = (ushort*)alloc(512*8*2);  ushort* w1ll = (ushort*)alloc(512*8*2);
  ushort* w1rh = (ushort*)alloc(512*8*2);  ushort* w1rl = (ushort*)alloc(512*8*2);
  ushort* w2lh = (ushort*)alloc(512*32*2); ushort* w2ll = (ushort*)alloc(512*32*2);
  ushort* w2rh = (ushort*)alloc(512*32*2); ushort* w2rl = (ushort*)alloc(512*32*2);
  ushort* w3lh = (ushort*)alloc(512*32*2); ushort* w3ll = (ushort*)alloc(512*32*2);
  ushort* w3rh = (ushort*)alloc(512*32*2); ushort* w3rl = (ushort*)alloc(512*32*2);

  hipMemsetAsync(deg, 0, (size_t)N_NODES*4, stream);
  hipMemsetAsync(cursor, 0, (size_t)N_NODES*4, stream);
  k_count_deg<<<N_EDGES/256, 256, 0, stream>>>(edst, deg);
  k_scan1<<<N_NODES/256, 256, 0, stream>>>(deg, row_ptr, dinv, bsum);
  k_scan2<<<1, 512, 0, stream>>>(bsum, row_ptr);
  k_scan3<<<N_NODES/256, 256, 0, stream>>>(row_ptr, bsum);
  k_scatter<<<N_EDGES/256, 256, 0, stream>>>(esrc, edst, row_ptr, cursor, csr);

  k_pack_x<<<(N_NODES*32)/256, 256, 0, stream>>>(x, Xhi, Xlo);
  k_pack_w<<<(256*32)/256, 256, 0, stream>>>(wl1, wr1, w1lh, w1ll, w1rh, w1rl, 1, IN_CH);
  k_pack_w<<<(256*128)/256, 256, 0, stream>>>(wl2, wr2, w2lh, w2ll, w2rh, w2rl, 4, 128);
  k_pack_w<<<(256*128)/256, 256, 0, stream>>>(wl3, wr3, w3lh, w3ll, w3rh, w3rl, 4, 128);
  k_transpose_cw<<<(32*HID*5 + 255)/256, 256, 0, stream>>>(cw, cwT);

  // layer 1: M1 = mean(x_nb); h1 = relu(M1@Wl1 + x@Wr1 + b1)  (K padded to 32)
  k_gather<<<NGRAPH*2, 1024, 0, stream>>>(Xhi, Xlo, Mhi, Mlo, row_ptr, csr, dinv, 1);
  k_gemm<1,0><<<N_NODES/128, 256, 0, stream>>>(Mhi, Mlo, Xhi, Xlo,
      w1lh, w1ll, w1rh, w1rl, b1, Hhi, Hlo, nullptr);
  // layer 2 (in-place h: each block reads only its own rows before its epilogue writes)
  k_gather<<<NGRAPH*8, 1024, 0, stream>>>(Hhi, Hlo, Mhi, Mlo, row_ptr, csr, dinv, 4);
  k_gemm<4,0><<<N_NODES/128, 256, 0, stream>>>(Mhi, Mlo, Hhi, Hlo,
      w2lh, w2ll, w2rh, w2rl, b2, Hhi, Hlo, nullptr);
  // layer 3 -> fp32 row-major H3
  k_gather<<<NGRAPH*8, 1024, 0, stream>>>(Hhi, Hlo, Mhi, Mlo, row_ptr, csr, dinv, 4);
  k_gemm<4,1><<<N_NODES/128, 256, 0, stream>>>(Mhi, Mlo, Hhi, Hlo,
      w3lh, w3ll, w3rh, w3rl, b3, nullptr, nullptr, H3);

  k_sortpool<<<NGRAPH, 1024, 0, stream>>>(H3, sel);
  k_head<<<NGRAPH, 256, 0, stream>>>(H3, sel, cwT, cb, l1w, l1b, l2w, l2b, out);
}

// Round 6
// 555.169 us; speedup vs baseline: 1.6178x; 1.3038x over previous
//
#include <hip/hip_runtime.h>
#include <hip/hip_bf16.h>
#include <hip/hip_fp16.h>

#define N_NODES 131072
#define N_PER   1024
#define NGRAPH  128
#define N_EDGES 2097152
#define KSP     30
#define HID     128
#define IN_CH   14
#define OUT_DIM 4

typedef __attribute__((ext_vector_type(8))) short    v8s;
typedef __attribute__((ext_vector_type(8))) _Float16 v8h;
typedef __attribute__((ext_vector_type(4))) float    v4f;

__device__ inline v8h as_h(v8s s){ union { v8s s; v8h h; } u; u.s = s; return u.h; }

// fp32 -> f16 hi + f16 lo (lo pre-scaled by 2^12). hi never denormal.
#define LOSCALE 4096.0f
#define INV_LOSCALE (1.0f/4096.0f)
__device__ inline void f2split(float v, ushort& hi, ushort& lo){
  float av = fabsf(v);
  __half h = (av < 6.103515625e-05f) ? __ushort_as_half((ushort)0) : __float2half(v);
  hi = __half_as_ushort(h);
  lo = __half_as_ushort(__float2half((v - __half2float(h)) * LOSCALE));
}
__device__ inline float f2join(ushort hi, ushort lo){
  return __half2float(__ushort_as_half(hi)) + __half2float(__ushort_as_half(lo)) * INV_LOSCALE;
}

// ---------------- CSR build ----------------
__global__ __launch_bounds__(256) void k_count_deg(const int* __restrict__ dst, int* __restrict__ deg){
  int e = blockIdx.x*256 + threadIdx.x;
  if (e < N_EDGES) atomicAdd(&deg[dst[e]], 1);
}

__global__ __launch_bounds__(256) void k_scan1(const int* __restrict__ deg, int* __restrict__ row_ptr,
                                               float* __restrict__ deg_inv, int* __restrict__ bsum){
  __shared__ int sh[256];
  int t = threadIdx.x;
  int e = blockIdx.x*256 + t;
  int d = deg[e];
  sh[t] = d; __syncthreads();
  for (int ofs=1; ofs<256; ofs<<=1){
    int v = sh[t];
    int add = (t>=ofs) ? sh[t-ofs] : 0;
    __syncthreads();
    sh[t] = v + add;
    __syncthreads();
  }
  row_ptr[e] = sh[t] - d;
  deg_inv[e] = d > 0 ? 1.0f/(float)d : 0.0f;
  if (t==255) bsum[blockIdx.x] = sh[255];
}

__global__ __launch_bounds__(512) void k_scan2(int* __restrict__ bsum, int* __restrict__ row_ptr){
  __shared__ int sh[512];
  int t = threadIdx.x;
  int v0 = bsum[t];
  sh[t] = v0; __syncthreads();
  for (int ofs=1; ofs<512; ofs<<=1){
    int v = sh[t];
    int add = (t>=ofs) ? sh[t-ofs] : 0;
    __syncthreads();
    sh[t] = v + add;
    __syncthreads();
  }
  bsum[t] = sh[t] - v0;
  if (t==511) row_ptr[N_NODES] = sh[511];
}

__global__ __launch_bounds__(256) void k_scan3(int* __restrict__ row_ptr, const int* __restrict__ bsum){
  int e = blockIdx.x*256 + threadIdx.x;
  row_ptr[e] += bsum[blockIdx.x];
}

__global__ __launch_bounds__(256) void k_scatter(const int* __restrict__ src, const int* __restrict__ dst,
                                                 const int* __restrict__ row_ptr, int* __restrict__ cursor,
                                                 int* __restrict__ csr){
  int e = blockIdx.x*256 + threadIdx.x;
  if (e < N_EDGES){
    int d = dst[e];
    int pos = atomicAdd(&cursor[d], 1);
    csr[row_ptr[d] + pos] = src[e];
  }
}

// ---------------- prep: pack x / W into MFMA-fragment layouts (f16 hi/lo planes) ----------------
// frag index for row-major X[N][K] (K = KC*32): (n,k) -> ((n>>4)*KC + (k>>5))*512
//   + (((k&31)>>3)*16 + (n&15))*8 + (k&7)
__global__ __launch_bounds__(256) void k_pack_x(const float* __restrict__ x,
                                                ushort* __restrict__ xhi, ushort* __restrict__ xlo){
  int i = blockIdx.x*256 + threadIdx.x;          // N_NODES*32
  int n = i >> 5, k = i & 31;
  float v = (k < IN_CH) ? x[n*IN_CH + k] : 0.0f;
  int dst = (n >> 4)*512 + ((k >> 3)*16 + (n & 15))*8 + (k & 7);
  ushort hi, lo; f2split(v, hi, lo);
  xhi[dst] = hi; xlo[dst] = lo;
}

__global__ __launch_bounds__(256) void k_pack_w(const float* __restrict__ wl, const float* __restrict__ wr,
    ushort* __restrict__ wlh, ushort* __restrict__ wll,
    ushort* __restrict__ wrh, ushort* __restrict__ wrl, int KC, int kin){
  int i = blockIdx.x*256 + threadIdx.x;
  int Kp = KC*32;
  if (i >= 256*Kp) return;
  int which = i / (128*Kp);
  int r = (i / Kp) & 127;
  int k = i % Kp;
  const float* w = which ? wr : wl;
  float v = (k < kin) ? w[r*kin + k] : 0.0f;
  ushort hi, lo; f2split(v, hi, lo);
  int dst = ((r >> 4)*KC + (k >> 5))*512 + ((((k & 31) >> 3))*16 + (r & 15))*8 + (k & 7);
  if (which){ wrh[dst] = hi; wrl[dst] = lo; }
  else      { wlh[dst] = hi; wll[dst] = lo; }
}

__global__ __launch_bounds__(256) void k_transpose_cw(const float* __restrict__ cw, float* __restrict__ cwT){
  int e = blockIdx.x*256 + threadIdx.x;          // 32*128*5
  if (e < 32*HID*5){
    int o = e / 640, rem = e % 640;
    cwT[rem*32 + o] = cw[e];
  }
}

// ---------------- gather: M[i] = mean_{j->i} H[j] (frag layout in/out) ----------------
// grid = NGRAPH*(2*KC); block = (graph g, 16-channel pass). 1024 thr.
// LDS staged as int32 fixed-point (2^18): cvt once per staged elem; per-edge work = int adds.
// DETERMINISM: int accumulation is order-independent under csr permutation.
#define FXS 262144.0f
__global__ __launch_bounds__(1024) void k_gather(
    const ushort* __restrict__ Hhi, const ushort* __restrict__ Hlo,
    ushort* __restrict__ Mhi, ushort* __restrict__ Mlo,
    const int* __restrict__ row_ptr, const int* __restrict__ csr,
    const float* __restrict__ dinv, int KC){
  __shared__ int ldsI[N_PER*20];                 // 80 KB
  int P = KC*2;
  int g = blockIdx.x / P, p = blockIdx.x % P;
  int kc = p >> 1, half = p & 1;
  int t = threadIdx.x;
  for (int it = t; it < 16384; it += 1024){
    int Tl = it >> 8, e = it & 255;
    int idx = (((g*64 + Tl)*KC + kc) << 9) + (half << 8) + e;
    float v = f2join(Hhi[idx], Hlo[idx]);
    int l = e >> 3, j = e & 7;
    int m = l & 15, qh = l >> 4;
    ldsI[(Tl*16 + m)*20 + qh*8 + j] = __float2int_rn(v*FXS);
  }
  __syncthreads();
  int o2 = t & 1, ns = t >> 1;
  #pragma unroll
  for (int rep = 0; rep < 2; ++rep){
    int n = ns + rep*512;
    int node = g*N_PER + n;
    int s = row_ptr[node], e = row_ptr[node+1];
    int a0=0,a1=0,a2=0,a3=0,a4=0,a5=0,a6=0,a7=0;
    int j2 = s;
    for (; j2 + 2 <= e; j2 += 2){
      int la = csr[j2] & (N_PER-1);
      int lb = csr[j2+1] & (N_PER-1);
      const int4* ra = (const int4*)&ldsI[la*20 + o2*8];
      const int4* rb = (const int4*)&ldsI[lb*20 + o2*8];
      int4 x0 = ra[0], x1 = ra[1], y0 = rb[0], y1 = rb[1];
      a0 += x0.x + y0.x; a1 += x0.y + y0.y; a2 += x0.z + y0.z; a3 += x0.w + y0.w;
      a4 += x1.x + y1.x; a5 += x1.y + y1.y; a6 += x1.z + y1.z; a7 += x1.w + y1.w;
    }
    if (j2 < e){
      int la = csr[j2] & (N_PER-1);
      const int4* ra = (const int4*)&ldsI[la*20 + o2*8];
      int4 x0 = ra[0], x1 = ra[1];
      a0 += x0.x; a1 += x0.y; a2 += x0.z; a3 += x0.w;
      a4 += x1.x; a5 += x1.y; a6 += x1.z; a7 += x1.w;
    }
    float di = dinv[node] * (1.0f/FXS);
    float mv[8] = {(float)a0*di,(float)a1*di,(float)a2*di,(float)a3*di,
                   (float)a4*di,(float)a5*di,(float)a6*di,(float)a7*di};
    int q = half*2 + o2;
    int base = (((g*64 + (n >> 4))*KC + kc) << 9) + (q*16 + (n & 15))*8;
    ushort hs[8], ls[8];
    #pragma unroll
    for (int ii = 0; ii < 8; ++ii) f2split(mv[ii], hs[ii], ls[ii]);
    *(ushort4*)&Mhi[base]   = make_ushort4(hs[0],hs[1],hs[2],hs[3]);
    *(ushort4*)&Mhi[base+4] = make_ushort4(hs[4],hs[5],hs[6],hs[7]);
    *(ushort4*)&Mlo[base]   = make_ushort4(ls[0],ls[1],ls[2],ls[3]);
    *(ushort4*)&Mlo[base+4] = make_ushort4(ls[4],ls[5],ls[6],ls[7]);
  }
}

// ---------------- GEMM: h = relu(M@Wl + H@Wr + b), fp16x2 dual-accumulator ----------------
// 256 thr = 4 waves; wave = 1 row-tile (16 rows) x 8 col-tiles (128 cols): 64 acc VGPRs
// (was 128 -> 1 wave/SIMD). B fragments staged per-kc in LDS (32 KB), shared by all waves.
template<int KCI, int MODE>   // MODE0: f16 hi/lo planes out (KC_out=4). MODE1: f16 hi plane + fp32 key (col 127).
__global__ __launch_bounds__(256, 3) void k_gemm(
    const ushort* __restrict__ Ah1, const ushort* __restrict__ Al1,
    const ushort* __restrict__ Ah2, const ushort* __restrict__ Al2,
    const ushort* __restrict__ wlh, const ushort* __restrict__ wll,
    const ushort* __restrict__ wrh, const ushort* __restrict__ wrl,
    const float* __restrict__ bias, ushort* Hho, ushort* Hlo2, float* key){
  __shared__ ushort smB[4*8*512];                // 32 KB: [region(4)][ct(8)][512]
  int t = threadIdx.x, w = t >> 6, l = t & 63;
  int q = l >> 4, m = l & 15;
  int t0 = blockIdx.x*4 + w;                     // row-tile (16 rows)
  const ushort* warr[4] = {wlh, wll, wrh, wrl};  // (src,plane) = (0,h),(0,l),(1,h),(1,l)
  v4f acc1[8], acc2[8];
  #pragma unroll
  for (int b = 0; b < 8; ++b){ acc1[b] = (v4f){0.f,0.f,0.f,0.f}; acc2[b] = (v4f){0.f,0.f,0.f,0.f}; }
  v8s* smv = (v8s*)smB;
  for (int kc = 0; kc < KCI; ++kc){
    __syncthreads();
    #pragma unroll
    for (int i2 = 0; i2 < 8; ++i2){
      int i = i2*256 + t;                        // 2048 v8s chunks
      int r = i >> 9, e = i & 511;
      int ct = e >> 6, j = e & 63;
      smv[(r*8 + ct)*64 + j] = *(const v8s*)(warr[r] + ((ct*KCI + kc) << 9) + j*8);
    }
    __syncthreads();
    int aoff = ((t0*KCI + kc) << 9) + l*8;
    v8h a1h = as_h(*(const v8s*)(Ah1 + aoff));
    v8h a1l = as_h(*(const v8s*)(Al1 + aoff));
    v8h a2h = as_h(*(const v8s*)(Ah2 + aoff));
    v8h a2l = as_h(*(const v8s*)(Al2 + aoff));
    #pragma unroll
    for (int ct = 0; ct < 8; ++ct){
      v8h b0h = as_h(smv[(0*8 + ct)*64 + l]);
      v8h b0l = as_h(smv[(1*8 + ct)*64 + l]);
      v8h b1h = as_h(smv[(2*8 + ct)*64 + l]);
      v8h b1l = as_h(smv[(3*8 + ct)*64 + l]);
      acc1[ct] = __builtin_amdgcn_mfma_f32_16x16x32_f16(a1h, b0h, acc1[ct], 0, 0, 0);
      acc2[ct] = __builtin_amdgcn_mfma_f32_16x16x32_f16(a1l, b0h, acc2[ct], 0, 0, 0);
      acc2[ct] = __builtin_amdgcn_mfma_f32_16x16x32_f16(a1h, b0l, acc2[ct], 0, 0, 0);
      acc1[ct] = __builtin_amdgcn_mfma_f32_16x16x32_f16(a2h, b1h, acc1[ct], 0, 0, 0);
      acc2[ct] = __builtin_amdgcn_mfma_f32_16x16x32_f16(a2l, b1h, acc2[ct], 0, 0, 0);
      acc2[ct] = __builtin_amdgcn_mfma_f32_16x16x32_f16(a2h, b1l, acc2[ct], 0, 0, 0);
    }
  }
  // epilogue: row = t0*16 + q*4 + r, col = ct*16 + m; dest frag KC_out = 4
  #pragma unroll
  for (int ct = 0; ct < 8; ++ct){
    float badd = bias[ct*16 + m];
    #pragma unroll
    for (int r = 0; r < 4; ++r){
      float v = fmaxf(acc1[ct][r] + acc2[ct][r]*INV_LOSCALE + badd, 0.0f);
      int kc2 = ct >> 1;
      int lane2 = ((ct & 1)*2 + (m >> 3))*16 + q*4 + r;
      int didx = ((t0*4 + kc2) << 9) + lane2*8 + (m & 7);
      if (MODE == 0){
        ushort hi, lo; f2split(v, hi, lo);
        Hho[didx] = hi; Hlo2[didx] = lo;
      } else {
        Hho[didx] = __half_as_ushort(__float2half(v));
        if (ct == 7 && m == 15) key[t0*16 + q*4 + r] = v;   // exact fp32 sort key (ch 127)
      }
    }
  }
}

// ---------------- sort-pool: coalesced fp32 key read ----------------
__global__ __launch_bounds__(1024) void k_sortpool(const float* __restrict__ keyv, int* __restrict__ sel){
  int g = blockIdx.x, t = threadIdx.x;
  __shared__ unsigned long long key[N_PER];
  __shared__ unsigned long long wred[16];
  float v = keyv[g*N_PER + t];                   // post-relu, v >= 0 -> bits monotone
  key[t] = (((unsigned long long)__float_as_uint(v)) << 10) | (unsigned long long)(N_PER-1 - t);
  __syncthreads();
  for (int r = 0; r < KSP; ++r){
    unsigned long long k = key[t];
    #pragma unroll
    for (int ofs = 32; ofs > 0; ofs >>= 1){
      unsigned long long o2 = __shfl_down(k, ofs, 64);
      if (o2 > k) k = o2;
    }
    if ((t & 63) == 0) wred[t >> 6] = k;
    __syncthreads();
    if (t == 0){
      unsigned long long mm = wred[0];
      #pragma unroll
      for (int j = 1; j < 16; ++j) if (wred[j] > mm) mm = wred[j];
      int idx = (N_PER-1) - (int)(mm & 1023ULL);
      sel[g*KSP + r] = idx;
      key[idx] = 0ULL;
    }
    __syncthreads();
  }
}

// ---------------- head: H3 read from f16 hi plane (frag layout, KC=4) ----------------
__global__ __launch_bounds__(256) void k_head(const ushort* __restrict__ Hhi, const int* __restrict__ sel,
    const float* __restrict__ cwT, const float* __restrict__ cb,
    const float* __restrict__ l1w, const float* __restrict__ l1b,
    const float* __restrict__ l2w, const float* __restrict__ l2b,
    float* __restrict__ out){
  __shared__ __align__(16) float toplds[KSP*HID];
  __shared__ float ypart[8][832];
  __shared__ __align__(16) float yv[832];
  __shared__ float zv[HID];
  int g = blockIdx.x, t = threadIdx.x;
  for (int e = t; e < KSP*HID; e += 256){
    int tt = e >> 7, c = e & 127;
    int n = g*N_PER + sel[g*KSP + tt];
    int idx = ((n >> 4)*4 + (c >> 5))*512 + (((c & 31) >> 3)*16 + (n & 15))*8 + (c & 7);
    toplds[e] = __half2float(__ushort_as_half(Hhi[idx]));
  }
  __syncthreads();
  int o = t & 31, cch = t >> 5;
  float acc[26];
  #pragma unroll
  for (int th = 0; th < 26; ++th) acc[th] = 0.0f;
  for (int c = cch*16; c < cch*16 + 16; ++c){
    float tcol[KSP];
    #pragma unroll
    for (int tt = 0; tt < KSP; ++tt) tcol[tt] = toplds[tt*HID + c];
    float w5[5];
    #pragma unroll
    for (int s = 0; s < 5; ++s) w5[s] = cwT[(c*5 + s)*32 + o];
    #pragma unroll
    for (int th = 0; th < 26; ++th){
      float a2 = acc[th];
      #pragma unroll
      for (int s = 0; s < 5; ++s) a2 += tcol[th + s]*w5[s];
      acc[th] = a2;
    }
  }
  #pragma unroll
  for (int th = 0; th < 26; ++th) ypart[cch][o*26 + th] = acc[th];
  __syncthreads();
  for (int idx = t; idx < 832; idx += 256){
    float s2 = 0.0f;
    #pragma unroll
    for (int j = 0; j < 8; ++j) s2 += ypart[j][idx];
    yv[idx] = fmaxf(s2 + cb[idx / 26], 0.0f);
  }
  __syncthreads();
  if (t < HID){
    float a3 = l1b[t];
    const float4* wr4 = (const float4*)&l1w[t*832];
    const float4* yr4 = (const float4*)yv;
    #pragma unroll 4
    for (int k = 0; k < 208; ++k){
      float4 wv = wr4[k]; float4 yq = yr4[k];
      a3 += wv.x*yq.x + wv.y*yq.y + wv.z*yq.z + wv.w*yq.w;
    }
    zv[t] = fmaxf(a3, 0.0f);
  }
  __syncthreads();
  if (t < OUT_DIM){
    float a4 = l2b[t];
    for (int j = 0; j < HID; ++j) a4 += zv[j]*l2w[t*HID + j];
    out[g*OUT_DIM + t] = a4;
  }
}

extern "C" void kernel_launch(void* const* d_in, const int* in_sizes, int n_in,
                              void* d_out, int out_size, void* d_ws, size_t ws_size,
                              hipStream_t stream){
  const float* x   = (const float*)d_in[0];
  const int*   ei  = (const int*)d_in[1];
  const float* wl1 = (const float*)d_in[3];
  const float* b1  = (const float*)d_in[4];
  const float* wr1 = (const float*)d_in[5];
  const float* wl2 = (const float*)d_in[6];
  const float* b2  = (const float*)d_in[7];
  const float* wr2 = (const float*)d_in[8];
  const float* wl3 = (const float*)d_in[9];
  const float* b3  = (const float*)d_in[10];
  const float* wr3 = (const float*)d_in[11];
  const float* cw  = (const float*)d_in[12];
  const float* cb  = (const float*)d_in[13];
  const float* l1w = (const float*)d_in[14];
  const float* l1b = (const float*)d_in[15];
  const float* l2w = (const float*)d_in[16];
  const float* l2b = (const float*)d_in[17];
  float* out = (float*)d_out;
  const int* esrc = ei;
  const int* edst = ei + N_EDGES;

  char* p = (char*)d_ws;
  auto alloc = [&](size_t bytes)->char*{ char* r = p; p += (bytes + 255) & ~(size_t)255; return r; };
  int*    deg     = (int*)alloc((size_t)N_NODES*4);
  int*    cursor  = (int*)alloc((size_t)N_NODES*4);
  int*    row_ptr = (int*)alloc((size_t)(N_NODES+1)*4);
  int*    bsum    = (int*)alloc(512*4);
  float*  dinv    = (float*)alloc((size_t)N_NODES*4);
  int*    csr     = (int*)alloc((size_t)N_EDGES*4);
  int*    sel     = (int*)alloc((size_t)NGRAPH*KSP*4);
  float*  cwT     = (float*)alloc((size_t)32*HID*5*4);
  float*  keyv    = (float*)alloc((size_t)N_NODES*4);
  ushort* Xhi     = (ushort*)alloc((size_t)N_NODES*32*2);   // 8.4 MB
  ushort* Xlo     = (ushort*)alloc((size_t)N_NODES*32*2);
  ushort* Mhi     = (ushort*)alloc((size_t)N_NODES*HID*2);  // 33.5 MB
  ushort* Mlo     = (ushort*)alloc((size_t)N_NODES*HID*2);
  ushort* Hhi     = (ushort*)alloc((size_t)N_NODES*HID*2);
  ushort* Hlo     = (ushort*)alloc((size_t)N_NODES*HID*2);
  ushort* w1lh = (ushort*)alloc(512*8*2);  ushort* w1ll = (ushort*)alloc(512*8*2);
  ushort* w1rh = (ushort*)alloc(512*8*2);  ushort* w1rl = (ushort*)alloc(512*8*2);
  ushort* w2lh = (ushort*)alloc(512*32*2); ushort* w2ll = (ushort*)alloc(512*32*2);
  ushort* w2rh = (ushort*)alloc(512*32*2); ushort* w2rl = (ushort*)alloc(512*32*2);
  ushort* w3lh = (ushort*)alloc(512*32*2); ushort* w3ll = (ushort*)alloc(512*32*2);
  ushort* w3rh = (ushort*)alloc(512*32*2); ushort* w3rl = (ushort*)alloc(512*32*2);

  hipMemsetAsync(deg, 0, (size_t)N_NODES*4, stream);
  hipMemsetAsync(cursor, 0, (size_t)N_NODES*4, stream);
  k_count_deg<<<N_EDGES/256, 256, 0, stream>>>(edst, deg);
  k_scan1<<<N_NODES/256, 256, 0, stream>>>(deg, row_ptr, dinv, bsum);
  k_scan2<<<1, 512, 0, stream>>>(bsum, row_ptr);
  k_scan3<<<N_NODES/256, 256, 0, stream>>>(row_ptr, bsum);
  k_scatter<<<N_EDGES/256, 256, 0, stream>>>(esrc, edst, row_ptr, cursor, csr);

  k_pack_x<<<(N_NODES*32)/256, 256, 0, stream>>>(x, Xhi, Xlo);
  k_pack_w<<<(256*32)/256, 256, 0, stream>>>(wl1, wr1, w1lh, w1ll, w1rh, w1rl, 1, IN_CH);
  k_pack_w<<<(256*128)/256, 256, 0, stream>>>(wl2, wr2, w2lh, w2ll, w2rh, w2rl, 4, 128);
  k_pack_w<<<(256*128)/256, 256, 0, stream>>>(wl3, wr3, w3lh, w3ll, w3rh, w3rl, 4, 128);
  k_transpose_cw<<<(32*HID*5 + 255)/256, 256, 0, stream>>>(cw, cwT);

  const int GB = N_NODES/64;       // 2048 gemm blocks (4 row-tiles each)

  // layer 1: M1 = mean(x_nb); h1 = relu(M1@Wl1 + x@Wr1 + b1)  (K padded to 32)
  k_gather<<<NGRAPH*2, 1024, 0, stream>>>(Xhi, Xlo, Mhi, Mlo, row_ptr, csr, dinv, 1);
  k_gemm<1,0><<<GB, 256, 0, stream>>>(Mhi, Mlo, Xhi, Xlo,
      w1lh, w1ll, w1rh, w1rl, b1, Hhi, Hlo, nullptr);
  // layer 2 (in-place h: each wave reads only its own rows before its epilogue writes)
  k_gather<<<NGRAPH*8, 1024, 0, stream>>>(Hhi, Hlo, Mhi, Mlo, row_ptr, csr, dinv, 4);
  k_gemm<4,0><<<GB, 256, 0, stream>>>(Mhi, Mlo, Hhi, Hlo,
      w2lh, w2ll, w2rh, w2rl, b2, Hhi, Hlo, nullptr);
  // layer 3 -> f16 hi plane (head input) + exact fp32 sort key (channel 127)
  k_gather<<<NGRAPH*8, 1024, 0, stream>>>(Hhi, Hlo, Mhi, Mlo, row_ptr, csr, dinv, 4);
  k_gemm<4,1><<<GB, 256, 0, stream>>>(Mhi, Mlo, Hhi, Hlo,
      w3lh, w3ll, w3rh, w3rl, b3, Hhi, nullptr, keyv);

  k_sortpool<<<NGRAPH, 1024, 0, stream>>>(keyv, sel);
  k_head<<<NGRAPH, 256, 0, stream>>>(Hhi, sel, cwT, cb, l1w, l1b, l2w, l2b, out);
}

// Round 7
// 426.120 us; speedup vs baseline: 2.1077x; 1.3028x over previous
//
#include <hip/hip_runtime.h>
#include <hip/hip_bf16.h>
#include <hip/hip_fp16.h>

#define N_NODES 131072
#define N_PER   1024
#define NGRAPH  128
#define N_EDGES 2097152
#define EPG     16384     // edges per graph
#define KSP     30
#define HID     128
#define IN_CH   14
#define OUT_DIM 4

typedef __attribute__((ext_vector_type(8))) short    v8s;
typedef __attribute__((ext_vector_type(8))) _Float16 v8h;
typedef __attribute__((ext_vector_type(4))) float    v4f;

__device__ inline v8h as_h(v8s s){ union { v8s s; v8h h; } u; u.s = s; return u.h; }

// fp32 -> f16 hi + f16 lo (lo pre-scaled by 2^12). hi never denormal.
#define LOSCALE 4096.0f
#define INV_LOSCALE (1.0f/4096.0f)
__device__ inline void f2split(float v, ushort& hi, ushort& lo){
  float av = fabsf(v);
  __half h = (av < 6.103515625e-05f) ? __ushort_as_half((ushort)0) : __float2half(v);
  hi = __half_as_ushort(h);
  lo = __half_as_ushort(__float2half((v - __half2float(h)) * LOSCALE));
}
__device__ inline float f2join(ushort hi, ushort lo){
  return __half2float(__ushort_as_half(hi)) + __half2float(__ushort_as_half(lo)) * INV_LOSCALE;
}

// ---------------- fused per-graph CSR build (count+scan+scatter in LDS) ----------------
// Edges are graph-grouped: edge e in graph e/EPG, src/dst in [g*N_PER,(g+1)*N_PER).
// One block per graph. csr stored as ushort LOCAL node index; coalesced uint writes out.
__global__ __launch_bounds__(1024) void k_csr(const int* __restrict__ src, const int* __restrict__ dst,
    ushort* __restrict__ csr, int* __restrict__ row_ptr, float* __restrict__ dinv){
  __shared__ ushort lcsr[EPG];     // 32 KB
  __shared__ int ldeg[N_PER];
  __shared__ int lrp[N_PER];
  __shared__ int lcur[N_PER];
  int g = blockIdx.x, t = threadIdx.x;
  int base = g*EPG;
  ldeg[t] = 0;
  __syncthreads();
  #pragma unroll
  for (int r = 0; r < EPG/1024; ++r)
    atomicAdd(&ldeg[dst[base + r*1024 + t] & (N_PER-1)], 1);
  __syncthreads();
  int d = ldeg[t];
  lrp[t] = d;
  __syncthreads();
  for (int ofs = 1; ofs < N_PER; ofs <<= 1){
    int v = lrp[t];
    int add = (t >= ofs) ? lrp[t-ofs] : 0;
    __syncthreads();
    lrp[t] = v + add;
    __syncthreads();
  }
  int ex = lrp[t] - d;               // exclusive prefix
  lcur[t] = ex;
  row_ptr[g*N_PER + t] = base + ex;
  dinv[g*N_PER + t] = d > 0 ? 1.0f/(float)d : 0.0f;
  if (g == NGRAPH-1 && t == 0) row_ptr[N_NODES] = N_EDGES;
  __syncthreads();
  #pragma unroll
  for (int r = 0; r < EPG/1024; ++r){
    int e = base + r*1024 + t;
    int dl = dst[e] & (N_PER-1);
    int pos = atomicAdd(&lcur[dl], 1);
    lcsr[pos] = (ushort)(src[e] & (N_PER-1));
  }
  __syncthreads();
  uint* gout = (uint*)(csr + base);
  const uint* lin = (const uint*)lcsr;
  #pragma unroll
  for (int r = 0; r < EPG/2048; ++r)
    gout[r*1024 + t] = lin[r*1024 + t];
}

// ---------------- prep: pack x / W into MFMA-fragment layouts (f16 hi/lo planes) ----------------
// frag index for row-major X[N][K] (K = KC*32): (n,k) -> ((n>>4)*KC + (k>>5))*512
//   + (((k&31)>>3)*16 + (n&15))*8 + (k&7)
__global__ __launch_bounds__(256) void k_pack_x(const float* __restrict__ x,
                                                ushort* __restrict__ xhi, ushort* __restrict__ xlo){
  int i = blockIdx.x*256 + threadIdx.x;          // N_NODES*32
  int n = i >> 5, k = i & 31;
  float v = (k < IN_CH) ? x[n*IN_CH + k] : 0.0f;
  int dst = (n >> 4)*512 + ((k >> 3)*16 + (n & 15))*8 + (k & 7);
  ushort hi, lo; f2split(v, hi, lo);
  xhi[dst] = hi; xlo[dst] = lo;
}

__global__ __launch_bounds__(256) void k_pack_w(const float* __restrict__ wl, const float* __restrict__ wr,
    ushort* __restrict__ wlh, ushort* __restrict__ wll,
    ushort* __restrict__ wrh, ushort* __restrict__ wrl, int KC, int kin){
  int i = blockIdx.x*256 + threadIdx.x;
  int Kp = KC*32;
  if (i >= 256*Kp) return;
  int which = i / (128*Kp);
  int r = (i / Kp) & 127;
  int k = i % Kp;
  const float* w = which ? wr : wl;
  float v = (k < kin) ? w[r*kin + k] : 0.0f;
  ushort hi, lo; f2split(v, hi, lo);
  int dst = ((r >> 4)*KC + (k >> 5))*512 + ((((k & 31) >> 3))*16 + (r & 15))*8 + (k & 7);
  if (which){ wrh[dst] = hi; wrl[dst] = lo; }
  else      { wlh[dst] = hi; wll[dst] = lo; }
}

__global__ __launch_bounds__(256) void k_transpose_cw(const float* __restrict__ cw, float* __restrict__ cwT){
  int e = blockIdx.x*256 + threadIdx.x;          // 32*128*5
  if (e < 32*HID*5){
    int o = e / 640, rem = e % 640;
    cwT[rem*32 + o] = cw[e];
  }
}

// ---------------- gather: M[i] = mean_{j->i} H[j] (frag layout in/out) ----------------
// grid = NGRAPH*(2*KC); block = (graph g, 16-channel pass). 1024 thr.
// LDS staged as int32 fixed-point (2^18): cvt once per staged elem; per-edge work = int adds.
// DETERMINISM: int accumulation is order-independent under csr permutation.
#define FXS 262144.0f
__global__ __launch_bounds__(1024) void k_gather(
    const ushort* __restrict__ Hhi, const ushort* __restrict__ Hlo,
    ushort* __restrict__ Mhi, ushort* __restrict__ Mlo,
    const int* __restrict__ row_ptr, const ushort* __restrict__ csr,
    const float* __restrict__ dinv, int KC){
  __shared__ int ldsI[N_PER*20];                 // 80 KB
  int P = KC*2;
  int g = blockIdx.x / P, p = blockIdx.x % P;
  int kc = p >> 1, half = p & 1;
  int t = threadIdx.x;
  for (int it = t; it < 16384; it += 1024){
    int Tl = it >> 8, e = it & 255;
    int idx = (((g*64 + Tl)*KC + kc) << 9) + (half << 8) + e;
    float v = f2join(Hhi[idx], Hlo[idx]);
    int l = e >> 3, j = e & 7;
    int m = l & 15, qh = l >> 4;
    ldsI[(Tl*16 + m)*20 + qh*8 + j] = __float2int_rn(v*FXS);
  }
  __syncthreads();
  int o2 = t & 1, ns = t >> 1;
  #pragma unroll
  for (int rep = 0; rep < 2; ++rep){
    int n = ns + rep*512;
    int node = g*N_PER + n;
    int s = row_ptr[node], e = row_ptr[node+1];
    int a0=0,a1=0,a2=0,a3=0,a4=0,a5=0,a6=0,a7=0;
    int j2 = s;
    for (; j2 + 2 <= e; j2 += 2){
      int la = csr[j2];
      int lb = csr[j2+1];
      const int4* ra = (const int4*)&ldsI[la*20 + o2*8];
      const int4* rb = (const int4*)&ldsI[lb*20 + o2*8];
      int4 x0 = ra[0], x1 = ra[1], y0 = rb[0], y1 = rb[1];
      a0 += x0.x + y0.x; a1 += x0.y + y0.y; a2 += x0.z + y0.z; a3 += x0.w + y0.w;
      a4 += x1.x + y1.x; a5 += x1.y + y1.y; a6 += x1.z + y1.z; a7 += x1.w + y1.w;
    }
    if (j2 < e){
      int la = csr[j2];
      const int4* ra = (const int4*)&ldsI[la*20 + o2*8];
      int4 x0 = ra[0], x1 = ra[1];
      a0 += x0.x; a1 += x0.y; a2 += x0.z; a3 += x0.w;
      a4 += x1.x; a5 += x1.y; a6 += x1.z; a7 += x1.w;
    }
    float di = dinv[node] * (1.0f/FXS);
    float mv[8] = {(float)a0*di,(float)a1*di,(float)a2*di,(float)a3*di,
                   (float)a4*di,(float)a5*di,(float)a6*di,(float)a7*di};
    int q = half*2 + o2;
    int base = (((g*64 + (n >> 4))*KC + kc) << 9) + (q*16 + (n & 15))*8;
    ushort hs[8], ls[8];
    #pragma unroll
    for (int ii = 0; ii < 8; ++ii) f2split(mv[ii], hs[ii], ls[ii]);
    *(ushort4*)&Mhi[base]   = make_ushort4(hs[0],hs[1],hs[2],hs[3]);
    *(ushort4*)&Mhi[base+4] = make_ushort4(hs[4],hs[5],hs[6],hs[7]);
    *(ushort4*)&Mlo[base]   = make_ushort4(ls[0],ls[1],ls[2],ls[3]);
    *(ushort4*)&Mlo[base+4] = make_ushort4(ls[4],ls[5],ls[6],ls[7]);
  }
}

// ---------------- GEMM: h = relu(M@Wl + H@Wr + b), fp16x2 dual-accumulator ----------------
// 256 thr = 4 waves; wave = 1 row-tile (16 rows) x 8 col-tiles (128 cols): 64 acc VGPRs.
// B fragments staged per-kc in LDS (32 KB), shared by all waves.
template<int KCI, int MODE>   // MODE0: f16 hi/lo planes out (KC_out=4). MODE1: f16 hi plane + fp32 key (col 127).
__global__ __launch_bounds__(256, 3) void k_gemm(
    const ushort* __restrict__ Ah1, const ushort* __restrict__ Al1,
    const ushort* __restrict__ Ah2, const ushort* __restrict__ Al2,
    const ushort* __restrict__ wlh, const ushort* __restrict__ wll,
    const ushort* __restrict__ wrh, const ushort* __restrict__ wrl,
    const float* __restrict__ bias, ushort* Hho, ushort* Hlo2, float* key){
  __shared__ ushort smB[4*8*512];                // 32 KB: [region(4)][ct(8)][512]
  int t = threadIdx.x, w = t >> 6, l = t & 63;
  int q = l >> 4, m = l & 15;
  int t0 = blockIdx.x*4 + w;                     // row-tile (16 rows)
  const ushort* warr[4] = {wlh, wll, wrh, wrl};  // (src,plane) = (0,h),(0,l),(1,h),(1,l)
  v4f acc1[8], acc2[8];
  #pragma unroll
  for (int b = 0; b < 8; ++b){ acc1[b] = (v4f){0.f,0.f,0.f,0.f}; acc2[b] = (v4f){0.f,0.f,0.f,0.f}; }
  v8s* smv = (v8s*)smB;
  for (int kc = 0; kc < KCI; ++kc){
    __syncthreads();
    #pragma unroll
    for (int i2 = 0; i2 < 8; ++i2){
      int i = i2*256 + t;                        // 2048 v8s chunks
      int r = i >> 9, e = i & 511;
      int ct = e >> 6, j = e & 63;
      smv[(r*8 + ct)*64 + j] = *(const v8s*)(warr[r] + ((ct*KCI + kc) << 9) + j*8);
    }
    __syncthreads();
    int aoff = ((t0*KCI + kc) << 9) + l*8;
    v8h a1h = as_h(*(const v8s*)(Ah1 + aoff));
    v8h a1l = as_h(*(const v8s*)(Al1 + aoff));
    v8h a2h = as_h(*(const v8s*)(Ah2 + aoff));
    v8h a2l = as_h(*(const v8s*)(Al2 + aoff));
    #pragma unroll
    for (int ct = 0; ct < 8; ++ct){
      v8h b0h = as_h(smv[(0*8 + ct)*64 + l]);
      v8h b0l = as_h(smv[(1*8 + ct)*64 + l]);
      v8h b1h = as_h(smv[(2*8 + ct)*64 + l]);
      v8h b1l = as_h(smv[(3*8 + ct)*64 + l]);
      acc1[ct] = __builtin_amdgcn_mfma_f32_16x16x32_f16(a1h, b0h, acc1[ct], 0, 0, 0);
      acc2[ct] = __builtin_amdgcn_mfma_f32_16x16x32_f16(a1l, b0h, acc2[ct], 0, 0, 0);
      acc2[ct] = __builtin_amdgcn_mfma_f32_16x16x32_f16(a1h, b0l, acc2[ct], 0, 0, 0);
      acc1[ct] = __builtin_amdgcn_mfma_f32_16x16x32_f16(a2h, b1h, acc1[ct], 0, 0, 0);
      acc2[ct] = __builtin_amdgcn_mfma_f32_16x16x32_f16(a2l, b1h, acc2[ct], 0, 0, 0);
      acc2[ct] = __builtin_amdgcn_mfma_f32_16x16x32_f16(a2h, b1l, acc2[ct], 0, 0, 0);
    }
  }
  // epilogue: row = t0*16 + q*4 + r, col = ct*16 + m; dest frag KC_out = 4
  #pragma unroll
  for (int ct = 0; ct < 8; ++ct){
    float badd = bias[ct*16 + m];
    #pragma unroll
    for (int r = 0; r < 4; ++r){
      float v = fmaxf(acc1[ct][r] + acc2[ct][r]*INV_LOSCALE + badd, 0.0f);
      int kc2 = ct >> 1;
      int lane2 = ((ct & 1)*2 + (m >> 3))*16 + q*4 + r;
      int didx = ((t0*4 + kc2) << 9) + lane2*8 + (m & 7);
      if (MODE == 0){
        ushort hi, lo; f2split(v, hi, lo);
        Hho[didx] = hi; Hlo2[didx] = lo;
      } else {
        Hho[didx] = __half_as_ushort(__float2half(v));
        if (ct == 7 && m == 15) key[t0*16 + q*4 + r] = v;   // exact fp32 sort key (ch 127)
      }
    }
  }
}

// ---------------- sort-pool: coalesced fp32 key read ----------------
__global__ __launch_bounds__(1024) void k_sortpool(const float* __restrict__ keyv, int* __restrict__ sel){
  int g = blockIdx.x, t = threadIdx.x;
  __shared__ unsigned long long key[N_PER];
  __shared__ unsigned long long wred[16];
  float v = keyv[g*N_PER + t];                   // post-relu, v >= 0 -> bits monotone
  key[t] = (((unsigned long long)__float_as_uint(v)) << 10) | (unsigned long long)(N_PER-1 - t);
  __syncthreads();
  for (int r = 0; r < KSP; ++r){
    unsigned long long k = key[t];
    #pragma unroll
    for (int ofs = 32; ofs > 0; ofs >>= 1){
      unsigned long long o2 = __shfl_down(k, ofs, 64);
      if (o2 > k) k = o2;
    }
    if ((t & 63) == 0) wred[t >> 6] = k;
    __syncthreads();
    if (t == 0){
      unsigned long long mm = wred[0];
      #pragma unroll
      for (int j = 1; j < 16; ++j) if (wred[j] > mm) mm = wred[j];
      int idx = (N_PER-1) - (int)(mm & 1023ULL);
      sel[g*KSP + r] = idx;
      key[idx] = 0ULL;
    }
    __syncthreads();
  }
}

// ---------------- head: H3 read from f16 hi plane (frag layout, KC=4) ----------------
__global__ __launch_bounds__(256) void k_head(const ushort* __restrict__ Hhi, const int* __restrict__ sel,
    const float* __restrict__ cwT, const float* __restrict__ cb,
    const float* __restrict__ l1w, const float* __restrict__ l1b,
    const float* __restrict__ l2w, const float* __restrict__ l2b,
    float* __restrict__ out){
  __shared__ __align__(16) float toplds[KSP*HID];
  __shared__ float ypart[8][832];
  __shared__ __align__(16) float yv[832];
  __shared__ float zv[HID];
  int g = blockIdx.x, t = threadIdx.x;
  for (int e = t; e < KSP*HID; e += 256){
    int tt = e >> 7, c = e & 127;
    int n = g*N_PER + sel[g*KSP + tt];
    int idx = ((n >> 4)*4 + (c >> 5))*512 + (((c & 31) >> 3)*16 + (n & 15))*8 + (c & 7);
    toplds[e] = __half2float(__ushort_as_half(Hhi[idx]));
  }
  __syncthreads();
  int o = t & 31, cch = t >> 5;
  float acc[26];
  #pragma unroll
  for (int th = 0; th < 26; ++th) acc[th] = 0.0f;
  for (int c = cch*16; c < cch*16 + 16; ++c){
    float tcol[KSP];
    #pragma unroll
    for (int tt = 0; tt < KSP; ++tt) tcol[tt] = toplds[tt*HID + c];
    float w5[5];
    #pragma unroll
    for (int s = 0; s < 5; ++s) w5[s] = cwT[(c*5 + s)*32 + o];
    #pragma unroll
    for (int th = 0; th < 26; ++th){
      float a2 = acc[th];
      #pragma unroll
      for (int s = 0; s < 5; ++s) a2 += tcol[th + s]*w5[s];
      acc[th] = a2;
    }
  }
  #pragma unroll
  for (int th = 0; th < 26; ++th) ypart[cch][o*26 + th] = acc[th];
  __syncthreads();
  for (int idx = t; idx < 832; idx += 256){
    float s2 = 0.0f;
    #pragma unroll
    for (int j = 0; j < 8; ++j) s2 += ypart[j][idx];
    yv[idx] = fmaxf(s2 + cb[idx / 26], 0.0f);
  }
  __syncthreads();
  if (t < HID){
    float a3 = l1b[t];
    const float4* wr4 = (const float4*)&l1w[t*832];
    const float4* yr4 = (const float4*)yv;
    #pragma unroll 4
    for (int k = 0; k < 208; ++k){
      float4 wv = wr4[k]; float4 yq = yr4[k];
      a3 += wv.x*yq.x + wv.y*yq.y + wv.z*yq.z + wv.w*yq.w;
    }
    zv[t] = fmaxf(a3, 0.0f);
  }
  __syncthreads();
  if (t < OUT_DIM){
    float a4 = l2b[t];
    for (int j = 0; j < HID; ++j) a4 += zv[j]*l2w[t*HID + j];
    out[g*OUT_DIM + t] = a4;
  }
}

extern "C" void kernel_launch(void* const* d_in, const int* in_sizes, int n_in,
                              void* d_out, int out_size, void* d_ws, size_t ws_size,
                              hipStream_t stream){
  const float* x   = (const float*)d_in[0];
  const int*   ei  = (const int*)d_in[1];
  const float* wl1 = (const float*)d_in[3];
  const float* b1  = (const float*)d_in[4];
  const float* wr1 = (const float*)d_in[5];
  const float* wl2 = (const float*)d_in[6];
  const float* b2  = (const float*)d_in[7];
  const float* wr2 = (const float*)d_in[8];
  const float* wl3 = (const float*)d_in[9];
  const float* b3  = (const float*)d_in[10];
  const float* wr3 = (const float*)d_in[11];
  const float* cw  = (const float*)d_in[12];
  const float* cb  = (const float*)d_in[13];
  const float* l1w = (const float*)d_in[14];
  const float* l1b = (const float*)d_in[15];
  const float* l2w = (const float*)d_in[16];
  const float* l2b = (const float*)d_in[17];
  float* out = (float*)d_out;
  const int* esrc = ei;
  const int* edst = ei + N_EDGES;

  char* p = (char*)d_ws;
  auto alloc = [&](size_t bytes)->char*{ char* r = p; p += (bytes + 255) & ~(size_t)255; return r; };
  int*    row_ptr = (int*)alloc((size_t)(N_NODES+1)*4);
  float*  dinv    = (float*)alloc((size_t)N_NODES*4);
  ushort* csr     = (ushort*)alloc((size_t)N_EDGES*2);
  int*    sel     = (int*)alloc((size_t)NGRAPH*KSP*4);
  float*  cwT     = (float*)alloc((size_t)32*HID*5*4);
  float*  keyv    = (float*)alloc((size_t)N_NODES*4);
  ushort* Xhi     = (ushort*)alloc((size_t)N_NODES*32*2);   // 8.4 MB
  ushort* Xlo     = (ushort*)alloc((size_t)N_NODES*32*2);
  ushort* Mhi     = (ushort*)alloc((size_t)N_NODES*HID*2);  // 33.5 MB
  ushort* Mlo     = (ushort*)alloc((size_t)N_NODES*HID*2);
  ushort* Hhi     = (ushort*)alloc((size_t)N_NODES*HID*2);
  ushort* Hlo     = (ushort*)alloc((size_t)N_NODES*HID*2);
  ushort* w1lh = (ushort*)alloc(512*8*2);  ushort* w1ll = (ushort*)alloc(512*8*2);
  ushort* w1rh = (ushort*)alloc(512*8*2);  ushort* w1rl = (ushort*)alloc(512*8*2);
  ushort* w2lh = (ushort*)alloc(512*32*2); ushort* w2ll = (ushort*)alloc(512*32*2);
  ushort* w2rh = (ushort*)alloc(512*32*2); ushort* w2rl = (ushort*)alloc(512*32*2);
  ushort* w3lh = (ushort*)alloc(512*32*2); ushort* w3ll = (ushort*)alloc(512*32*2);
  ushort* w3rh = (ushort*)alloc(512*32*2); ushort* w3rl = (ushort*)alloc(512*32*2);

  k_csr<<<NGRAPH, 1024, 0, stream>>>(esrc, edst, csr, row_ptr, dinv);

  k_pack_x<<<(N_NODES*32)/256, 256, 0, stream>>>(x, Xhi, Xlo);
  k_pack_w<<<(256*32)/256, 256, 0, stream>>>(wl1, wr1, w1lh, w1ll, w1rh, w1rl, 1, IN_CH);
  k_pack_w<<<(256*128)/256, 256, 0, stream>>>(wl2, wr2, w2lh, w2ll, w2rh, w2rl, 4, 128);
  k_pack_w<<<(256*128)/256, 256, 0, stream>>>(wl3, wr3, w3lh, w3ll, w3rh, w3rl, 4, 128);
  k_transpose_cw<<<(32*HID*5 + 255)/256, 256, 0, stream>>>(cw, cwT);

  const int GB = N_NODES/64;       // 2048 gemm blocks (4 row-tiles each)

  // layer 1: M1 = mean(x_nb); h1 = relu(M1@Wl1 + x@Wr1 + b1)  (K padded to 32)
  k_gather<<<NGRAPH*2, 1024, 0, stream>>>(Xhi, Xlo, Mhi, Mlo, row_ptr, csr, dinv, 1);
  k_gemm<1,0><<<GB, 256, 0, stream>>>(Mhi, Mlo, Xhi, Xlo,
      w1lh, w1ll, w1rh, w1rl, b1, Hhi, Hlo, nullptr);
  // layer 2 (in-place h: each wave reads only its own rows before its epilogue writes)
  k_gather<<<NGRAPH*8, 1024, 0, stream>>>(Hhi, Hlo, Mhi, Mlo, row_ptr, csr, dinv, 4);
  k_gemm<4,0><<<GB, 256, 0, stream>>>(Mhi, Mlo, Hhi, Hlo,
      w2lh, w2ll, w2rh, w2rl, b2, Hhi, Hlo, nullptr);
  // layer 3 -> f16 hi plane (head input) + exact fp32 sort key (channel 127)
  k_gather<<<NGRAPH*8, 1024, 0, stream>>>(Hhi, Hlo, Mhi, Mlo, row_ptr, csr, dinv, 4);
  k_gemm<4,1><<<GB, 256, 0, stream>>>(Mhi, Mlo, Hhi, Hlo,
      w3lh, w3ll, w3rh, w3rl, b3, Hhi, nullptr, keyv);

  k_sortpool<<<NGRAPH, 1024, 0, stream>>>(keyv, sel);
  k_head<<<NGRAPH, 256, 0, stream>>>(Hhi, sel, cwT, cb, l1w, l1b, l2w, l2b, out);
}

// Round 8
// 410.479 us; speedup vs baseline: 2.1880x; 1.0381x over previous
//
#include <hip/hip_runtime.h>
#include <hip/hip_bf16.h>
#include <hip/hip_fp16.h>

#define N_NODES 131072
#define N_PER   1024
#define NGRAPH  128
#define N_EDGES 2097152
#define EPG     16384     // edges per graph
#define KSP     30
#define HID     128
#define IN_CH   14
#define OUT_DIM 4

typedef __attribute__((ext_vector_type(8))) short    v8s;
typedef __attribute__((ext_vector_type(8))) _Float16 v8h;
typedef __attribute__((ext_vector_type(4))) float    v4f;

__device__ inline v8h as_h(v8s s){ union { v8s s; v8h h; } u; u.s = s; return u.h; }

// fp32 -> f16 hi + f16 lo (lo pre-scaled by 2^12). hi never denormal.
#define LOSCALE 4096.0f
#define INV_LOSCALE (1.0f/4096.0f)
__device__ inline void f2split(float v, ushort& hi, ushort& lo){
  float av = fabsf(v);
  __half h = (av < 6.103515625e-05f) ? __ushort_as_half((ushort)0) : __float2half(v);
  hi = __half_as_ushort(h);
  lo = __half_as_ushort(__float2half((v - __half2float(h)) * LOSCALE));
}
__device__ inline float f2join(ushort hi, ushort lo){
  return __half2float(__ushort_as_half(hi)) + __half2float(__ushort_as_half(lo)) * INV_LOSCALE;
}

// ---------------- fused per-graph CSR build (count+scan+scatter in LDS) ----------------
__global__ __launch_bounds__(1024) void k_csr(const int* __restrict__ src, const int* __restrict__ dst,
    ushort* __restrict__ csr, int* __restrict__ row_ptr, float* __restrict__ dinv){
  __shared__ ushort lcsr[EPG];     // 32 KB
  __shared__ int ldeg[N_PER];
  __shared__ int lrp[N_PER];
  __shared__ int lcur[N_PER];
  int g = blockIdx.x, t = threadIdx.x;
  int base = g*EPG;
  ldeg[t] = 0;
  __syncthreads();
  #pragma unroll
  for (int r = 0; r < EPG/1024; ++r)
    atomicAdd(&ldeg[dst[base + r*1024 + t] & (N_PER-1)], 1);
  __syncthreads();
  int d = ldeg[t];
  lrp[t] = d;
  __syncthreads();
  for (int ofs = 1; ofs < N_PER; ofs <<= 1){
    int v = lrp[t];
    int add = (t >= ofs) ? lrp[t-ofs] : 0;
    __syncthreads();
    lrp[t] = v + add;
    __syncthreads();
  }
  int ex = lrp[t] - d;               // exclusive prefix
  lcur[t] = ex;
  row_ptr[g*N_PER + t] = base + ex;
  dinv[g*N_PER + t] = d > 0 ? 1.0f/(float)d : 0.0f;
  if (g == NGRAPH-1 && t == 0) row_ptr[N_NODES] = N_EDGES;
  __syncthreads();
  #pragma unroll
  for (int r = 0; r < EPG/1024; ++r){
    int e = base + r*1024 + t;
    int dl = dst[e] & (N_PER-1);
    int pos = atomicAdd(&lcur[dl], 1);
    lcsr[pos] = (ushort)(src[e] & (N_PER-1));
  }
  __syncthreads();
  uint* gout = (uint*)(csr + base);
  const uint* lin = (const uint*)lcsr;
  #pragma unroll
  for (int r = 0; r < EPG/2048; ++r)
    gout[r*1024 + t] = lin[r*1024 + t];
}

// ---------------- prep: pack x / W into MFMA-fragment layouts (f16 hi/lo planes) ----------------
__global__ __launch_bounds__(256) void k_pack_x(const float* __restrict__ x,
                                                ushort* __restrict__ xhi, ushort* __restrict__ xlo){
  int i = blockIdx.x*256 + threadIdx.x;          // N_NODES*32
  int n = i >> 5, k = i & 31;
  float v = (k < IN_CH) ? x[n*IN_CH + k] : 0.0f;
  int dst = (n >> 4)*512 + ((k >> 3)*16 + (n & 15))*8 + (k & 7);
  ushort hi, lo; f2split(v, hi, lo);
  xhi[dst] = hi; xlo[dst] = lo;
}

__global__ __launch_bounds__(256) void k_pack_w(const float* __restrict__ wl, const float* __restrict__ wr,
    ushort* __restrict__ wlh, ushort* __restrict__ wll,
    ushort* __restrict__ wrh, ushort* __restrict__ wrl, int KC, int kin){
  int i = blockIdx.x*256 + threadIdx.x;
  int Kp = KC*32;
  if (i >= 256*Kp) return;
  int which = i / (128*Kp);
  int r = (i / Kp) & 127;
  int k = i % Kp;
  const float* w = which ? wr : wl;
  float v = (k < kin) ? w[r*kin + k] : 0.0f;
  ushort hi, lo; f2split(v, hi, lo);
  int dst = ((r >> 4)*KC + (k >> 5))*512 + ((((k & 31) >> 3))*16 + (r & 15))*8 + (k & 7);
  if (which){ wrh[dst] = hi; wrl[dst] = lo; }
  else      { wlh[dst] = hi; wll[dst] = lo; }
}

__global__ __launch_bounds__(256) void k_transpose_cw(const float* __restrict__ cw, float* __restrict__ cwT){
  int e = blockIdx.x*256 + threadIdx.x;          // 32*128*5
  if (e < 32*HID*5){
    int o = e / 640, rem = e % 640;
    cwT[rem*32 + o] = cw[e];
  }
}

// ---------------- gather: M[i] = mean_{j->i} H[j] (frag layout in/out) ----------------
#define FXS 262144.0f
__global__ __launch_bounds__(1024) void k_gather(
    const ushort* __restrict__ Hhi, const ushort* __restrict__ Hlo,
    ushort* __restrict__ Mhi, ushort* __restrict__ Mlo,
    const int* __restrict__ row_ptr, const ushort* __restrict__ csr,
    const float* __restrict__ dinv, int KC){
  __shared__ int ldsI[N_PER*20];                 // 80 KB
  int P = KC*2;
  int g = blockIdx.x / P, p = blockIdx.x % P;
  int kc = p >> 1, half = p & 1;
  int t = threadIdx.x;
  for (int it = t; it < 16384; it += 1024){
    int Tl = it >> 8, e = it & 255;
    int idx = (((g*64 + Tl)*KC + kc) << 9) + (half << 8) + e;
    float v = f2join(Hhi[idx], Hlo[idx]);
    int l = e >> 3, j = e & 7;
    int m = l & 15, qh = l >> 4;
    ldsI[(Tl*16 + m)*20 + qh*8 + j] = __float2int_rn(v*FXS);
  }
  __syncthreads();
  int o2 = t & 1, ns = t >> 1;
  #pragma unroll
  for (int rep = 0; rep < 2; ++rep){
    int n = ns + rep*512;
    int node = g*N_PER + n;
    int s = row_ptr[node], e = row_ptr[node+1];
    int a0=0,a1=0,a2=0,a3=0,a4=0,a5=0,a6=0,a7=0;
    int j2 = s;
    for (; j2 + 2 <= e; j2 += 2){
      int la = csr[j2];
      int lb = csr[j2+1];
      const int4* ra = (const int4*)&ldsI[la*20 + o2*8];
      const int4* rb = (const int4*)&ldsI[lb*20 + o2*8];
      int4 x0 = ra[0], x1 = ra[1], y0 = rb[0], y1 = rb[1];
      a0 += x0.x + y0.x; a1 += x0.y + y0.y; a2 += x0.z + y0.z; a3 += x0.w + y0.w;
      a4 += x1.x + y1.x; a5 += x1.y + y1.y; a6 += x1.z + y1.z; a7 += x1.w + y1.w;
    }
    if (j2 < e){
      int la = csr[j2];
      const int4* ra = (const int4*)&ldsI[la*20 + o2*8];
      int4 x0 = ra[0], x1 = ra[1];
      a0 += x0.x; a1 += x0.y; a2 += x0.z; a3 += x0.w;
      a4 += x1.x; a5 += x1.y; a6 += x1.z; a7 += x1.w;
    }
    float di = dinv[node] * (1.0f/FXS);
    float mv[8] = {(float)a0*di,(float)a1*di,(float)a2*di,(float)a3*di,
                   (float)a4*di,(float)a5*di,(float)a6*di,(float)a7*di};
    int q = half*2 + o2;
    int base = (((g*64 + (n >> 4))*KC + kc) << 9) + (q*16 + (n & 15))*8;
    ushort hs[8], ls[8];
    #pragma unroll
    for (int ii = 0; ii < 8; ++ii) f2split(mv[ii], hs[ii], ls[ii]);
    *(ushort4*)&Mhi[base]   = make_ushort4(hs[0],hs[1],hs[2],hs[3]);
    *(ushort4*)&Mhi[base+4] = make_ushort4(hs[4],hs[5],hs[6],hs[7]);
    *(ushort4*)&Mlo[base]   = make_ushort4(ls[0],ls[1],ls[2],ls[3]);
    *(ushort4*)&Mlo[base+4] = make_ushort4(ls[4],ls[5],ls[6],ls[7]);
  }
}

// ---------------- GEMM: h = relu(M@Wl + H@Wr + b), fp16x2 dual-accumulator ----------------
// 256 thr = 4 waves. Block = 64 rows x 128 cols. Wave = 2 row-tiles x 4 col-tiles
// (waves split the col dim -> B LDS reads halved vs 1rtx8ct). B staged in 32 KB LDS,
// software-pipelined: fetch B(kc+1) into regs during compute(kc), commit after read-barrier.
template<int KCI, int MODE>   // MODE0: f16 hi/lo planes out (KC_out=4). MODE1: f16 hi plane + fp32 key (col 127).
__global__ __launch_bounds__(256, 2) void k_gemm(
    const ushort* __restrict__ Ah1, const ushort* __restrict__ Al1,
    const ushort* __restrict__ Ah2, const ushort* __restrict__ Al2,
    const ushort* __restrict__ wlh, const ushort* __restrict__ wll,
    const ushort* __restrict__ wrh, const ushort* __restrict__ wrl,
    const float* __restrict__ bias, ushort* Hho, ushort* Hlo2, float* key){
  __shared__ ushort smB[4*8*512];                // 32 KB: [region(4)][ct(8)][lane(64)][8]
  int t = threadIdx.x, w = t >> 6, l = t & 63;
  int q = l >> 4, m = l & 15;
  int rtl = (w & 1)*2;                           // local row-tile base (0 or 2)
  int ctb = (w >> 1)*4;                          // col-tile base (0 or 4)
  int t0 = blockIdx.x*4;                         // block = 4 row-tiles (64 rows)
  const ushort* warr[4] = {wlh, wll, wrh, wrl};  // (src,plane) = (0,h),(0,l),(1,h),(1,l)
  v4f acc1[2][4], acc2[2][4];                    // [rr][cc]
  #pragma unroll
  for (int a = 0; a < 2; ++a)
    #pragma unroll
    for (int b = 0; b < 4; ++b){ acc1[a][b] = (v4f){0.f,0.f,0.f,0.f}; acc2[a][b] = (v4f){0.f,0.f,0.f,0.f}; }
  v8s* smv = (v8s*)smB;
  v8s pre[8];
  // prefetch B(kc=0) and commit
  #pragma unroll
  for (int i2 = 0; i2 < 8; ++i2){
    int i = i2*256 + t; int r = i >> 9, e2 = i & 511, ct = e2 >> 6, j = e2 & 63;
    pre[i2] = *(const v8s*)(warr[r] + ((ct*KCI + 0) << 9) + j*8);
  }
  #pragma unroll
  for (int i2 = 0; i2 < 8; ++i2) smv[i2*256 + t] = pre[i2];

  for (int kc = 0; kc < KCI; ++kc){
    __syncthreads();                             // B(kc) visible in LDS
    if (kc + 1 < KCI){
      #pragma unroll
      for (int i2 = 0; i2 < 8; ++i2){
        int i = i2*256 + t; int r = i >> 9, e2 = i & 511, ct = e2 >> 6, j = e2 & 63;
        pre[i2] = *(const v8s*)(warr[r] + ((ct*KCI + kc + 1) << 9) + j*8);
      }
    }
    // A fragments for this wave's 2 row-tiles (8 loads, batched)
    v8h a1h[2], a1l[2], a2h[2], a2l[2];
    #pragma unroll
    for (int rr = 0; rr < 2; ++rr){
      int aoff = (((t0 + rtl + rr)*KCI + kc) << 9) + l*8;
      a1h[rr] = as_h(*(const v8s*)(Ah1 + aoff));
      a1l[rr] = as_h(*(const v8s*)(Al1 + aoff));
      a2h[rr] = as_h(*(const v8s*)(Ah2 + aoff));
      a2l[rr] = as_h(*(const v8s*)(Al2 + aoff));
    }
    #pragma unroll
    for (int cc = 0; cc < 4; ++cc){
      int ct = ctb + cc;
      v8h b0h = as_h(smv[(0*8 + ct)*64 + l]);
      v8h b0l = as_h(smv[(1*8 + ct)*64 + l]);
      v8h b1h = as_h(smv[(2*8 + ct)*64 + l]);
      v8h b1l = as_h(smv[(3*8 + ct)*64 + l]);
      #pragma unroll
      for (int rr = 0; rr < 2; ++rr){
        acc1[rr][cc] = __builtin_amdgcn_mfma_f32_16x16x32_f16(a1h[rr], b0h, acc1[rr][cc], 0, 0, 0);
        acc2[rr][cc] = __builtin_amdgcn_mfma_f32_16x16x32_f16(a1l[rr], b0h, acc2[rr][cc], 0, 0, 0);
        acc2[rr][cc] = __builtin_amdgcn_mfma_f32_16x16x32_f16(a1h[rr], b0l, acc2[rr][cc], 0, 0, 0);
        acc1[rr][cc] = __builtin_amdgcn_mfma_f32_16x16x32_f16(a2h[rr], b1h, acc1[rr][cc], 0, 0, 0);
        acc2[rr][cc] = __builtin_amdgcn_mfma_f32_16x16x32_f16(a2l[rr], b1h, acc2[rr][cc], 0, 0, 0);
        acc2[rr][cc] = __builtin_amdgcn_mfma_f32_16x16x32_f16(a2h[rr], b1l, acc2[rr][cc], 0, 0, 0);
      }
    }
    __syncthreads();                             // all waves done reading B(kc)
    if (kc + 1 < KCI){
      #pragma unroll
      for (int i2 = 0; i2 < 8; ++i2) smv[i2*256 + t] = pre[i2];
    }
  }
  // epilogue: row = (t0+rtl+rr)*16 + q*4 + r, col = (ctb+cc)*16 + m; dest frag KC_out = 4
  #pragma unroll
  for (int cc = 0; cc < 4; ++cc){
    int ct_g = ctb + cc;
    float badd = bias[ct_g*16 + m];
    #pragma unroll
    for (int rr = 0; rr < 2; ++rr){
      int T = t0 + rtl + rr;
      #pragma unroll
      for (int r = 0; r < 4; ++r){
        float v = fmaxf(acc1[rr][cc][r] + acc2[rr][cc][r]*INV_LOSCALE + badd, 0.0f);
        int lane2 = ((ct_g & 1)*2 + (m >> 3))*16 + q*4 + r;
        int didx = ((T*4 + (ct_g >> 1)) << 9) + lane2*8 + (m & 7);
        if (MODE == 0){
          ushort hi, lo; f2split(v, hi, lo);
          Hho[didx] = hi; Hlo2[didx] = lo;
        } else {
          Hho[didx] = __half_as_ushort(__float2half(v));
          if (ct_g == 7 && m == 15) key[T*16 + q*4 + r] = v;   // exact fp32 sort key (ch 127)
        }
      }
    }
  }
}

// ---------------- sort-pool: coalesced fp32 key read ----------------
__global__ __launch_bounds__(1024) void k_sortpool(const float* __restrict__ keyv, int* __restrict__ sel){
  int g = blockIdx.x, t = threadIdx.x;
  __shared__ unsigned long long key[N_PER];
  __shared__ unsigned long long wred[16];
  float v = keyv[g*N_PER + t];                   // post-relu, v >= 0 -> bits monotone
  key[t] = (((unsigned long long)__float_as_uint(v)) << 10) | (unsigned long long)(N_PER-1 - t);
  __syncthreads();
  for (int r = 0; r < KSP; ++r){
    unsigned long long k = key[t];
    #pragma unroll
    for (int ofs = 32; ofs > 0; ofs >>= 1){
      unsigned long long o2 = __shfl_down(k, ofs, 64);
      if (o2 > k) k = o2;
    }
    if ((t & 63) == 0) wred[t >> 6] = k;
    __syncthreads();
    if (t == 0){
      unsigned long long mm = wred[0];
      #pragma unroll
      for (int j = 1; j < 16; ++j) if (wred[j] > mm) mm = wred[j];
      int idx = (N_PER-1) - (int)(mm & 1023ULL);
      sel[g*KSP + r] = idx;
      key[idx] = 0ULL;
    }
    __syncthreads();
  }
}

// ---------------- head: H3 read from f16 hi plane (frag layout, KC=4) ----------------
__global__ __launch_bounds__(256) void k_head(const ushort* __restrict__ Hhi, const int* __restrict__ sel,
    const float* __restrict__ cwT, const float* __restrict__ cb,
    const float* __restrict__ l1w, const float* __restrict__ l1b,
    const float* __restrict__ l2w, const float* __restrict__ l2b,
    float* __restrict__ out){
  __shared__ __align__(16) float toplds[KSP*HID];
  __shared__ float ypart[8][832];
  __shared__ __align__(16) float yv[832];
  __shared__ float zv[HID];
  int g = blockIdx.x, t = threadIdx.x;
  for (int e = t; e < KSP*HID; e += 256){
    int tt = e >> 7, c = e & 127;
    int n = g*N_PER + sel[g*KSP + tt];
    int idx = ((n >> 4)*4 + (c >> 5))*512 + (((c & 31) >> 3)*16 + (n & 15))*8 + (c & 7);
    toplds[e] = __half2float(__ushort_as_half(Hhi[idx]));
  }
  __syncthreads();
  int o = t & 31, cch = t >> 5;
  float acc[26];
  #pragma unroll
  for (int th = 0; th < 26; ++th) acc[th] = 0.0f;
  for (int c = cch*16; c < cch*16 + 16; ++c){
    float tcol[KSP];
    #pragma unroll
    for (int tt = 0; tt < KSP; ++tt) tcol[tt] = toplds[tt*HID + c];
    float w5[5];
    #pragma unroll
    for (int s = 0; s < 5; ++s) w5[s] = cwT[(c*5 + s)*32 + o];
    #pragma unroll
    for (int th = 0; th < 26; ++th){
      float a2 = acc[th];
      #pragma unroll
      for (int s = 0; s < 5; ++s) a2 += tcol[th + s]*w5[s];
      acc[th] = a2;
    }
  }
  #pragma unroll
  for (int th = 0; th < 26; ++th) ypart[cch][o*26 + th] = acc[th];
  __syncthreads();
  for (int idx = t; idx < 832; idx += 256){
    float s2 = 0.0f;
    #pragma unroll
    for (int j = 0; j < 8; ++j) s2 += ypart[j][idx];
    yv[idx] = fmaxf(s2 + cb[idx / 26], 0.0f);
  }
  __syncthreads();
  if (t < HID){
    float a3 = l1b[t];
    const float4* wr4 = (const float4*)&l1w[t*832];
    const float4* yr4 = (const float4*)yv;
    #pragma unroll 4
    for (int k = 0; k < 208; ++k){
      float4 wv = wr4[k]; float4 yq = yr4[k];
      a3 += wv.x*yq.x + wv.y*yq.y + wv.z*yq.z + wv.w*yq.w;
    }
    zv[t] = fmaxf(a3, 0.0f);
  }
  __syncthreads();
  if (t < OUT_DIM){
    float a4 = l2b[t];
    for (int j = 0; j < HID; ++j) a4 += zv[j]*l2w[t*HID + j];
    out[g*OUT_DIM + t] = a4;
  }
}

extern "C" void kernel_launch(void* const* d_in, const int* in_sizes, int n_in,
                              void* d_out, int out_size, void* d_ws, size_t ws_size,
                              hipStream_t stream){
  const float* x   = (const float*)d_in[0];
  const int*   ei  = (const int*)d_in[1];
  const float* wl1 = (const float*)d_in[3];
  const float* b1  = (const float*)d_in[4];
  const float* wr1 = (const float*)d_in[5];
  const float* wl2 = (const float*)d_in[6];
  const float* b2  = (const float*)d_in[7];
  const float* wr2 = (const float*)d_in[8];
  const float* wl3 = (const float*)d_in[9];
  const float* b3  = (const float*)d_in[10];
  const float* wr3 = (const float*)d_in[11];
  const float* cw  = (const float*)d_in[12];
  const float* cb  = (const float*)d_in[13];
  const float* l1w = (const float*)d_in[14];
  const float* l1b = (const float*)d_in[15];
  const float* l2w = (const float*)d_in[16];
  const float* l2b = (const float*)d_in[17];
  float* out = (float*)d_out;
  const int* esrc = ei;
  const int* edst = ei + N_EDGES;

  char* p = (char*)d_ws;
  auto alloc = [&](size_t bytes)->char*{ char* r = p; p += (bytes + 255) & ~(size_t)255; return r; };
  int*    row_ptr = (int*)alloc((size_t)(N_NODES+1)*4);
  float*  dinv    = (float*)alloc((size_t)N_NODES*4);
  ushort* csr     = (ushort*)alloc((size_t)N_EDGES*2);
  int*    sel     = (int*)alloc((size_t)NGRAPH*KSP*4);
  float*  cwT     = (float*)alloc((size_t)32*HID*5*4);
  float*  keyv    = (float*)alloc((size_t)N_NODES*4);
  ushort* Xhi     = (ushort*)alloc((size_t)N_NODES*32*2);   // 8.4 MB
  ushort* Xlo     = (ushort*)alloc((size_t)N_NODES*32*2);
  ushort* Mhi     = (ushort*)alloc((size_t)N_NODES*HID*2);  // 33.5 MB
  ushort* Mlo     = (ushort*)alloc((size_t)N_NODES*HID*2);
  ushort* Hhi     = (ushort*)alloc((size_t)N_NODES*HID*2);
  ushort* Hlo     = (ushort*)alloc((size_t)N_NODES*HID*2);
  ushort* w1lh = (ushort*)alloc(512*8*2);  ushort* w1ll = (ushort*)alloc(512*8*2);
  ushort* w1rh = (ushort*)alloc(512*8*2);  ushort* w1rl = (ushort*)alloc(512*8*2);
  ushort* w2lh = (ushort*)alloc(512*32*2); ushort* w2ll = (ushort*)alloc(512*32*2);
  ushort* w2rh = (ushort*)alloc(512*32*2); ushort* w2rl = (ushort*)alloc(512*32*2);
  ushort* w3lh = (ushort*)alloc(512*32*2); ushort* w3ll = (ushort*)alloc(512*32*2);
  ushort* w3rh = (ushort*)alloc(512*32*2); ushort* w3rl = (ushort*)alloc(512*32*2);

  k_csr<<<NGRAPH, 1024, 0, stream>>>(esrc, edst, csr, row_ptr, dinv);

  k_pack_x<<<(N_NODES*32)/256, 256, 0, stream>>>(x, Xhi, Xlo);
  k_pack_w<<<(256*32)/256, 256, 0, stream>>>(wl1, wr1, w1lh, w1ll, w1rh, w1rl, 1, IN_CH);
  k_pack_w<<<(256*128)/256, 256, 0, stream>>>(wl2, wr2, w2lh, w2ll, w2rh, w2rl, 4, 128);
  k_pack_w<<<(256*128)/256, 256, 0, stream>>>(wl3, wr3, w3lh, w3ll, w3rh, w3rl, 4, 128);
  k_transpose_cw<<<(32*HID*5 + 255)/256, 256, 0, stream>>>(cw, cwT);

  const int GB = N_NODES/64;       // 2048 gemm blocks (4 row-tiles each)

  // layer 1: M1 = mean(x_nb); h1 = relu(M1@Wl1 + x@Wr1 + b1)  (K padded to 32)
  k_gather<<<NGRAPH*2, 1024, 0, stream>>>(Xhi, Xlo, Mhi, Mlo, row_ptr, csr, dinv, 1);
  k_gemm<1,0><<<GB, 256, 0, stream>>>(Mhi, Mlo, Xhi, Xlo,
      w1lh, w1ll, w1rh, w1rl, b1, Hhi, Hlo, nullptr);
  // layer 2 (in-place h: block reads only its own rows as A before its epilogue writes)
  k_gather<<<NGRAPH*8, 1024, 0, stream>>>(Hhi, Hlo, Mhi, Mlo, row_ptr, csr, dinv, 4);
  k_gemm<4,0><<<GB, 256, 0, stream>>>(Mhi, Mlo, Hhi, Hlo,
      w2lh, w2ll, w2rh, w2rl, b2, Hhi, Hlo, nullptr);
  // layer 3 -> f16 hi plane (head input) + exact fp32 sort key (channel 127)
  k_gather<<<NGRAPH*8, 1024, 0, stream>>>(Hhi, Hlo, Mhi, Mlo, row_ptr, csr, dinv, 4);
  k_gemm<4,1><<<GB, 256, 0, stream>>>(Mhi, Mlo, Hhi, Hlo,
      w3lh, w3ll, w3rh, w3rl, b3, Hhi, nullptr, keyv);

  k_sortpool<<<NGRAPH, 1024, 0, stream>>>(keyv, sel);
  k_head<<<NGRAPH, 256, 0, stream>>>(Hhi, sel, cwT, cb, l1w, l1b, l2w, l2b, out);
}